// Round 9
// baseline (586.134 us; speedup 1.0000x reference)
//
#include <hip/hip_runtime.h>
#include <cstdint>
#include <cmath>

#define N0G 100000
#define N1G 25000
#define N2G 6250
#define E0G 1600000
#define E1G 400000
#define E2G 100000
#define KCH 6
#define NCLS 40
#define RPB 512            // rows per bucket (9 bits local row)
#define NBLK 240           // binning blocks
#define PAYB 17            // payload bits (col or edge idx < 131072)
#define SCT 16             // scan elems per thread
#define SCB (256 * SCT)    // scan elems per block

static inline int cdiv(long a, long b){ return (int)((a + b - 1) / b); }

// ================= deterministic bucket CSR build =================
// entry = (row & 511) << 17 | payload.  payload = col (graph) or edge idx (pool)

__global__ __launch_bounds__(256) void k_phist(const int* __restrict__ row, int E, int chunk,
                                               int* __restrict__ gh, int nbkt){
  __shared__ int h[256];
  for (int i = threadIdx.x; i < nbkt; i += 256) h[i] = 0;
  __syncthreads();
  int e0 = blockIdx.x * chunk, e1 = min(E, e0 + chunk);
  for (int e = e0 + threadIdx.x; e < e1; e += 256)
    atomicAdd(&h[row[e] >> 9], 1);
  __syncthreads();
  for (int i = threadIdx.x; i < nbkt; i += 256)
    gh[i * NBLK + blockIdx.x] = h[i];
}

// parallel flat exclusive scan of gh[M]: A) per-block sums, C) offset + local scan
__global__ __launch_bounds__(256) void k_scanA(const int* __restrict__ gh, int M, int* __restrict__ bsum){
  __shared__ int sh[256];
  int base = blockIdx.x * SCB + threadIdx.x * SCT;
  int s = 0;
#pragma unroll
  for (int j = 0; j < SCT; j++){ int i = base + j; if (i < M) s += gh[i]; }
  sh[threadIdx.x] = s; __syncthreads();
  for (int o = 128; o > 0; o >>= 1){
    if (threadIdx.x < o) sh[threadIdx.x] += sh[threadIdx.x + o];
    __syncthreads();
  }
  if (threadIdx.x == 0) bsum[blockIdx.x] = sh[0];
}

__global__ __launch_bounds__(256) void k_scanC(int* __restrict__ gh, int M, const int* __restrict__ bsum,
                                               int* __restrict__ rp, int N, int E){
  __shared__ int sh[256];
  __shared__ int blockoff;
  if (threadIdx.x == 0){
    int off = 0;
    for (int j = 0; j < (int)blockIdx.x; j++) off += bsum[j];
    blockoff = off;
  }
  int base = blockIdx.x * SCB + threadIdx.x * SCT;
  int v[SCT]; int s = 0;
#pragma unroll
  for (int j = 0; j < SCT; j++){ int i = base + j; v[j] = (i < M) ? gh[i] : 0; s += v[j]; }
  sh[threadIdx.x] = s;
  __syncthreads();
  for (int o = 1; o < 256; o <<= 1){
    int t = (threadIdx.x >= o) ? sh[threadIdx.x - o] : 0;
    __syncthreads();
    sh[threadIdx.x] += t;
    __syncthreads();
  }
  int excl = blockoff + sh[threadIdx.x] - s;
#pragma unroll
  for (int j = 0; j < SCT; j++){
    int i = base + j;
    if (i < M){ gh[i] = excl; excl += v[j]; }
  }
  if (blockIdx.x == 0 && threadIdx.x == 0) rp[N] = E;
}

template<bool POOL>
__global__ __launch_bounds__(256) void k_pscatter(const int* __restrict__ row, const int* __restrict__ col,
                                                  int E, int chunk, const int* __restrict__ gh,
                                                  unsigned* __restrict__ ebuf, int nbkt){
  __shared__ int cur[256];
  for (int i = threadIdx.x; i < nbkt; i += 256) cur[i] = gh[i * NBLK + blockIdx.x];
  __syncthreads();
  int e0 = blockIdx.x * chunk, e1 = min(E, e0 + chunk);
  for (int e = e0 + threadIdx.x; e < e1; e += 256){
    int r = row[e];
    int dst = atomicAdd(&cur[r >> 9], 1);
    unsigned pay = POOL ? (unsigned)e : (unsigned)col[e];
    ebuf[dst] = ((unsigned)(r & 511) << PAYB) | pay;
  }
}

template<bool POOL>
__global__ __launch_bounds__(512) void k_bfinal(const unsigned* __restrict__ ebuf,
                                                const int* __restrict__ gh, int nbkt, int N, int E,
                                                const int* __restrict__ pcol, const float* __restrict__ pval,
                                                int* __restrict__ rp, float* __restrict__ dinv,
                                                int* __restrict__ cs, float* __restrict__ wv){
  __shared__ int h[512];
  __shared__ int cur[512];
  int b = blockIdx.x;
  int e0 = gh[b * NBLK];
  int e1 = (b + 1 < nbkt) ? gh[(b + 1) * NBLK] : E;
  int r0 = b * RPB;
  int t = threadIdx.x;
  h[t] = 0;
  __syncthreads();
  for (int e = e0 + t; e < e1; e += 512)
    atomicAdd(&h[ebuf[e] >> PAYB], 1);
  __syncthreads();
  int cnt = h[t];
  __syncthreads();
  for (int o = 1; o < 512; o <<= 1){
    int tmp = (t >= o) ? h[t - o] : 0;
    __syncthreads();
    h[t] += tmp;
    __syncthreads();
  }
  int excl = h[t] - cnt;
  cur[t] = excl;
  if (r0 + t < N){
    rp[r0 + t] = e0 + excl;
    if (!POOL) dinv[r0 + t] = cnt > 0 ? rsqrtf((float)cnt) : 0.f;
  }
  __syncthreads();
  for (int e = e0 + t; e < e1; e += 512){
    unsigned u = ebuf[e];
    int p = atomicAdd(&cur[u >> PAYB], 1);
    int dst = e0 + p;
    if (POOL){
      int ei = (int)(u & ((1u << PAYB) - 1));
      cs[dst] = pcol[ei]; wv[dst] = pval[ei];
    } else {
      cs[dst] = (int)(u & ((1u << PAYB) - 1));
    }
  }
}

// ================= CSR gathers =================
__global__ __launch_bounds__(256) void k_gather3(const int* __restrict__ rp, const int* __restrict__ cs,
                          const float* __restrict__ src, const float* __restrict__ dinv,
                          const float* __restrict__ sub, float* __restrict__ dst,
                          int N, float scale){
  int n = blockIdx.x * blockDim.x + threadIdx.x;
  if (n >= N) return;
  int e0 = rp[n], e1 = rp[n + 1];
  float a0 = 0.f, a1 = 0.f, a2 = 0.f;
  for (int e = e0; e < e1; e++){
    int c = cs[e];
    float w = dinv[c];
    const float* sp = src + c * 3;
    a0 = fmaf(w, sp[0], a0);
    a1 = fmaf(w, sp[1], a1);
    a2 = fmaf(w, sp[2], a2);
  }
  float m = -scale * dinv[n];
  float r0 = m * a0, r1 = m * a1, r2 = m * a2;
  if (sub){ r0 -= sub[n * 3 + 0]; r1 -= sub[n * 3 + 1]; r2 -= sub[n * 3 + 2]; }
  dst[n * 3 + 0] = r0; dst[n * 3 + 1] = r1; dst[n * 3 + 2] = r2;
}

// F multiple of 4; lane-group of L=F/4 per node, float4 per lane.
template<int F>
__global__ __launch_bounds__(256) void k_gatherT(const int* __restrict__ rp, const int* __restrict__ cs,
                          const float* __restrict__ src, const float* __restrict__ dinv,
                          const float* __restrict__ sub, float* __restrict__ dst,
                          int N, float scale){
  constexpr int L = F / 4;
  int tid = blockIdx.x * 256 + threadIdx.x;
  int n = tid / L, q = tid % L;
  if (n >= N) return;
  const float4* src4 = (const float4*)src;
  int e0 = rp[n], e1 = rp[n + 1];
  float4 acc = make_float4(0.f, 0.f, 0.f, 0.f);
  for (int e = e0; e < e1; e++){
    int c = cs[e];
    float w = dinv[c];
    float4 v = src4[(long)c * L + q];
    acc.x = fmaf(w, v.x, acc.x); acc.y = fmaf(w, v.y, acc.y);
    acc.z = fmaf(w, v.z, acc.z); acc.w = fmaf(w, v.w, acc.w);
  }
  float m = -scale * dinv[n];
  float4 r = make_float4(m * acc.x, m * acc.y, m * acc.z, m * acc.w);
  if (sub){
    float4 sv = ((const float4*)sub)[(long)n * L + q];
    r.x -= sv.x; r.y -= sv.y; r.z -= sv.z; r.w -= sv.w;
  }
  ((float4*)dst)[(long)n * L + q] = r;
}

template<int F>
__global__ __launch_bounds__(256) void k_gatherP(const int* __restrict__ rp, const int* __restrict__ cs,
                          const float* __restrict__ wv, const float* __restrict__ h,
                          float* __restrict__ dst, int N){
  constexpr int L = F / 4;
  int tid = blockIdx.x * 256 + threadIdx.x;
  int n = tid / L, q = tid % L;
  if (n >= N) return;
  const float4* h4 = (const float4*)h;
  int e0 = rp[n], e1 = rp[n + 1];
  float4 acc = make_float4(0.f, 0.f, 0.f, 0.f);
  for (int e = e0; e < e1; e++){
    int c = cs[e];
    float w = wv[e];
    float4 v = h4[(long)c * L + q];
    acc.x = fmaf(w, v.x, acc.x); acc.y = fmaf(w, v.y, acc.y);
    acc.z = fmaf(w, v.z, acc.z); acc.w = fmaf(w, v.w, acc.w);
  }
  ((float4*)dst)[(long)n * L + q] = acc;
}

// ================= dense cheb contraction, LDS-tiled =================
// C[N, FO] = X6[N, 6F] @ W[6F, FO] + b,  X6 row = concat(x_row, T1..T5 rows).
// Block: NT = (256/(FO/4)) * R nodes. X6 tile staged in LDS (pitch +4 dwords).
// W read direct from global (L1/L2 resident), coalesced across o4 lanes.
template<int F, int FO, int R, bool RELU>
__global__ __launch_bounds__(256) void k_cheb_tile(const float* __restrict__ x, const float* __restrict__ T, int N,
                           const float* __restrict__ W, const float* __restrict__ b,
                           float* __restrict__ out){
  constexpr int OQ4  = FO / 4;
  constexpr int NSUB = 256 / OQ4;
  constexpr int NT   = NSUB * R;
  constexpr int F6   = KCH * F;
  constexpr int PITCH = F6 + 4;      // dwords; +4 keeps float4 alignment, skews banks
  __shared__ float X[NT * PITCH];
  int n0 = blockIdx.x * NT;

  if constexpr (F == 3){
    // scalar staging: slab k is a contiguous run of NT*F floats at rows n0..
    for (int i = threadIdx.x; i < NT * F6; i += 256){
      int k = i / (NT * F);
      int idx = i - k * (NT * F);
      int node = idx / F, j = idx - node * F;
      const float* src = (k == 0) ? x : (T + (size_t)(k - 1) * N * F);
      float v = (n0 + node < N) ? src[(long)n0 * F + idx] : 0.f;
      X[node * PITCH + k * F + j] = v;
    }
  } else {
    constexpr int L = F / 4;
    for (int i = threadIdx.x; i < NT * KCH * L; i += 256){
      int k = i / (NT * L);
      int idx = i - k * (NT * L);
      int node = idx / L, q = idx - node * L;
      const float4* src4 = (const float4*)((k == 0) ? x : (T + (size_t)(k - 1) * N * F));
      float4 v = make_float4(0.f, 0.f, 0.f, 0.f);
      if (n0 + node < N) v = src4[(long)n0 * L + idx];
      *(float4*)&X[node * PITCH + k * F + 4 * q] = v;
    }
  }
  __syncthreads();

  int o4   = threadIdx.x & (OQ4 - 1);
  int nsub = threadIdx.x >> (OQ4 == 8 ? 3 : (OQ4 == 16 ? 4 : 5));
  const float4* W4 = (const float4*)W;       // [F6][OQ4]
  float4 bb = ((const float4*)b)[o4];
  float4 acc[R];
#pragma unroll
  for (int r = 0; r < R; r++) acc[r] = bb;

#pragma unroll 4
  for (int f = 0; f < F6; f++){
    float4 w = W4[(long)f * OQ4 + o4];
#pragma unroll
    for (int r = 0; r < R; r++){
      float v = X[(nsub * R + r) * PITCH + f];
      acc[r].x = fmaf(v, w.x, acc[r].x); acc[r].y = fmaf(v, w.y, acc[r].y);
      acc[r].z = fmaf(v, w.z, acc[r].z); acc[r].w = fmaf(v, w.w, acc[r].w);
    }
  }
#pragma unroll
  for (int r = 0; r < R; r++){
    int n = n0 + nsub * R + r;
    if (n < N){
      float4 o = acc[r];
      if (RELU){
        o.x = fmaxf(o.x, 0.f); o.y = fmaxf(o.y, 0.f);
        o.z = fmaxf(o.z, 0.f); o.w = fmaxf(o.w, 0.f);
      }
      ((float4*)out)[(long)n * OQ4 + o4] = o;
    }
  }
}

// ================= final hidden GEMM + global max + classifier =================
__device__ __forceinline__ unsigned fmap(float x){
  unsigned u = __float_as_uint(x);
  return (u & 0x80000000u) ? ~u : (u | 0x80000000u);
}
__device__ __forceinline__ float funmap(unsigned u){
  return (u & 0x80000000u) ? __uint_as_float(u ^ 0x80000000u) : __uint_as_float(~u);
}

// grid (8, ceil(N/32)): block = 32 nodes x 128 outputs (32 float4).
// thread = 1 float4 output x 4 nodes (acc[4] = 16 VGPR). LDS tile [n][f4] 16 KB.
#define NT 32
__global__ __launch_bounds__(256) void k_hidden_max(const float* __restrict__ h2, const float* __restrict__ Wh,
                             const float* __restrict__ bh, unsigned* __restrict__ maxed, int N){
  __shared__ float4 sh4[NT * 32];        // 16 KB
  int n0 = blockIdx.y * NT;
  for (int i = threadIdx.x; i < NT * 32; i += 256){
    int n = i >> 5;
    float4 v = make_float4(0.f, 0.f, 0.f, 0.f);
    if (n0 + n < N) v = ((const float4*)h2)[(long)(n0 + n) * 32 + (i & 31)];
    sh4[i] = v;
  }
  __syncthreads();
  int o4l  = threadIdx.x & 31;           // o4 within tile
  int nsub = threadIdx.x >> 5;           // 0..7, 4 nodes each
  int o4   = blockIdx.x * 32 + o4l;      // global float4 output index
  const float4* Wh4 = (const float4*)Wh;
  float4 acc[4];
#pragma unroll
  for (int j = 0; j < 4; j++) acc[j] = make_float4(0.f, 0.f, 0.f, 0.f);
  for (int f4 = 0; f4 < 32; f4++){
    float4 w0 = Wh4[(long)(4 * f4 + 0) * 256 + o4];
    float4 w1 = Wh4[(long)(4 * f4 + 1) * 256 + o4];
    float4 w2 = Wh4[(long)(4 * f4 + 2) * 256 + o4];
    float4 w3 = Wh4[(long)(4 * f4 + 3) * 256 + o4];
#pragma unroll
    for (int j = 0; j < 4; j++){
      float4 hv = sh4[(nsub * 4 + j) * 32 + f4];
      acc[j].x = fmaf(hv.x, w0.x, acc[j].x); acc[j].y = fmaf(hv.x, w0.y, acc[j].y);
      acc[j].z = fmaf(hv.x, w0.z, acc[j].z); acc[j].w = fmaf(hv.x, w0.w, acc[j].w);
      acc[j].x = fmaf(hv.y, w1.x, acc[j].x); acc[j].y = fmaf(hv.y, w1.y, acc[j].y);
      acc[j].z = fmaf(hv.y, w1.z, acc[j].z); acc[j].w = fmaf(hv.y, w1.w, acc[j].w);
      acc[j].x = fmaf(hv.z, w2.x, acc[j].x); acc[j].y = fmaf(hv.z, w2.y, acc[j].y);
      acc[j].z = fmaf(hv.z, w2.z, acc[j].z); acc[j].w = fmaf(hv.z, w2.w, acc[j].w);
      acc[j].x = fmaf(hv.w, w3.x, acc[j].x); acc[j].y = fmaf(hv.w, w3.y, acc[j].y);
      acc[j].z = fmaf(hv.w, w3.z, acc[j].z); acc[j].w = fmaf(hv.w, w3.w, acc[j].w);
    }
  }
  float4 m = make_float4(-INFINITY, -INFINITY, -INFINITY, -INFINITY);
#pragma unroll
  for (int j = 0; j < 4; j++){
    if (n0 + nsub * 4 + j < N){
      m.x = fmaxf(m.x, acc[j].x); m.y = fmaxf(m.y, acc[j].y);
      m.z = fmaxf(m.z, acc[j].z); m.w = fmaxf(m.w, acc[j].w);
    }
  }
  __syncthreads();
  sh4[nsub * 32 + o4l] = m;
  __syncthreads();
  if (nsub == 0){
#pragma unroll
    for (int s = 1; s < 8; s++){
      float4 o = sh4[s * 32 + o4l];
      m.x = fmaxf(m.x, o.x); m.y = fmaxf(m.y, o.y);
      m.z = fmaxf(m.z, o.z); m.w = fmaxf(m.w, o.w);
    }
    float4 b4 = ((const float4*)bh)[o4];
    atomicMax(&maxed[4 * o4 + 0], fmap(m.x + b4.x));
    atomicMax(&maxed[4 * o4 + 1], fmap(m.y + b4.y));
    atomicMax(&maxed[4 * o4 + 2], fmap(m.z + b4.z));
    atomicMax(&maxed[4 * o4 + 3], fmap(m.w + b4.w));
  }
}

// 40 blocks (one per class) x 64 lanes; wave shuffle reduce.
__global__ __launch_bounds__(64) void k_final(const unsigned* __restrict__ maxed, const float* __restrict__ Wl,
                        const float* __restrict__ bl, float* __restrict__ out){
  int c = blockIdx.x;
  int l = threadIdx.x;
  float acc = 0.f;
  for (int o = l; o < 1024; o += 64)
    acc = fmaf(funmap(maxed[o]), Wl[o * NCLS + c], acc);
  for (int off = 32; off > 0; off >>= 1)
    acc += __shfl_down(acc, off);
  if (l == 0) out[c] = acc + bl[c];
}

// ================= drivers =================
static void run_scan(int* gh, int M, int* bsum, int* rp, int N, int E, hipStream_t s){
  int nb = cdiv(M, SCB);
  k_scanA<<<nb, 256, 0, s>>>(gh, M, bsum);
  k_scanC<<<nb, 256, 0, s>>>(gh, M, bsum, rp, N, E);
}

template<int F, int FO, int R, bool RELU>
static void run_cheb(const int* row, const int* col, int E, int N,
                     const float* x, const float* W, const float* b, float* out,
                     unsigned* ebuf, int* cs, float* T,
                     int* rp, float* dinv, int* gh, int* bsum, hipStream_t s){
  int nbkt = cdiv(N, RPB);
  int chunk = cdiv(E, NBLK);
  k_phist<<<NBLK, 256, 0, s>>>(row, E, chunk, gh, nbkt);
  run_scan(gh, nbkt * NBLK, bsum, rp, N, E, s);
  k_pscatter<false><<<NBLK, 256, 0, s>>>(row, col, E, chunk, gh, ebuf, nbkt);
  k_bfinal<false><<<nbkt, 512, 0, s>>>(ebuf, gh, nbkt, N, E, nullptr, nullptr, rp, dinv, cs, nullptr);

  const float* src = x; const float* sub = nullptr; float scale = 1.f;
  for (int k = 1; k < KCH; k++){
    float* Tk = T + (size_t)(k - 1) * N * F;
    if constexpr (F == 3)
      k_gather3<<<cdiv(N, 256), 256, 0, s>>>(rp, cs, src, dinv, sub, Tk, N, scale);
    else
      k_gatherT<F><<<cdiv((long)N * (F / 4), 256), 256, 0, s>>>(rp, cs, src, dinv, sub, Tk, N, scale);
    sub = src; src = Tk; scale = 2.f;
  }
  constexpr int NTC = (256 / (FO / 4)) * R;
  k_cheb_tile<F, FO, R, RELU><<<cdiv(N, NTC), 256, 0, s>>>(x, T, N, W, b, out);
}

template<int F>
static void run_pool(const int* row, const int* col, const float* val, int E, int Nout,
                     const float* h, float* out, unsigned* ebuf, int* cs, float* wv,
                     int* rp, int* gh, int* bsum, hipStream_t s){
  int nbkt = cdiv(Nout, RPB);
  int chunk = cdiv(E, NBLK);
  k_phist<<<NBLK, 256, 0, s>>>(row, E, chunk, gh, nbkt);
  run_scan(gh, nbkt * NBLK, bsum, rp, Nout, E, s);
  k_pscatter<true><<<NBLK, 256, 0, s>>>(row, col, E, chunk, gh, ebuf, nbkt);
  k_bfinal<true><<<nbkt, 512, 0, s>>>(ebuf, gh, nbkt, Nout, E, col, val, rp, nullptr, cs, wv);
  k_gatherP<F><<<cdiv((long)Nout * (F / 4), 256), 256, 0, s>>>(rp, cs, wv, h, out, Nout);
}

extern "C" void kernel_launch(void* const* d_in, const int* in_sizes, int n_in,
                              void* d_out, int out_size, void* d_ws, size_t ws_size,
                              hipStream_t stream){
  const float* pos = (const float*)d_in[0];
  const int*   ei0 = (const int*)d_in[1];
  const int*   ei1 = (const int*)d_in[2];
  const int*   ei2 = (const int*)d_in[3];
  const int*   p0r = (const int*)d_in[4];
  const int*   p0c = (const int*)d_in[5];
  const float* p0v = (const float*)d_in[6];
  const int*   p1r = (const int*)d_in[7];
  const int*   p1c = (const int*)d_in[8];
  const float* p1v = (const float*)d_in[9];
  const float* W0  = (const float*)d_in[10]; const float* b0 = (const float*)d_in[11];
  const float* W1  = (const float*)d_in[12]; const float* b1 = (const float*)d_in[13];
  const float* W2  = (const float*)d_in[14]; const float* b2 = (const float*)d_in[15];
  const float* Wh  = (const float*)d_in[16]; const float* bh = (const float*)d_in[17];
  const float* Wl  = (const float*)d_in[18]; const float* bl = (const float*)d_in[19];
  float* out = (float*)d_out;

  // workspace layout (float-sized units)
  float* SCR = (float*)d_ws;                 // 4.8M floats, per-stage overlays
  float* hA  = SCR + 4800000;                // 3.2M  (N0*32 / N2*128)
  float* hB  = hA + 3200000;                 // 1.6M  (N1*64)
  float* hC  = hB + 1600000;                 // 0.8M  (N1*32 / N2*64)
  int* rp     = (int*)(hC + 800000);         // 100001
  float* dinv = (float*)(rp + 100001);       // 100000
  int* gh     = (int*)(dinv + 100000);       // 47040 (196*240 max)
  int* bsum   = gh + 47040;                  // 16
  unsigned* maxed = (unsigned*)(bsum + 16);  // 1024

  // layer 0: cheb(pos) -> hA [N0,32], relu.  SCR: ebuf 1.6M | cs 1.6M | T 1.5M
  run_cheb<3, 32, 1, true>(ei0, ei0 + E0G, E0G, N0G, pos, W0, b0, hA,
                        (unsigned*)SCR, (int*)(SCR + 1600000), SCR + 3200000,
                        rp, dinv, gh, bsum, stream);

  // pool 0: hA -> hC [N1,32].  SCR: ebuf 100K | cs 100K | wv 100K
  run_pool<32>(p0r, p0c, p0v, N0G, N1G, hA, hC,
               (unsigned*)SCR, (int*)(SCR + 100000), SCR + 200000,
               rp, gh, bsum, stream);

  // layer 1: cheb(hC) -> hB [N1,64], relu.  SCR: ebuf 400K | cs 400K | T 4M
  run_cheb<32, 64, 1, true>(ei1, ei1 + E1G, E1G, N1G, hC, W1, b1, hB,
                         (unsigned*)SCR, (int*)(SCR + 400000), SCR + 800000,
                         rp, dinv, gh, bsum, stream);

  // pool 1: hB -> hC [N2,64].  SCR: ebuf 25K | cs 25K | wv 25K
  run_pool<64>(p1r, p1c, p1v, N1G, N2G, hB, hC,
               (unsigned*)SCR, (int*)(SCR + 25000), SCR + 50000,
               rp, gh, bsum, stream);

  // layer 2: cheb(hC) -> hA [N2,128], no relu.  SCR: ebuf 100K | cs 100K | T 2M
  run_cheb<64, 128, 1, false>(ei2, ei2 + E2G, E2G, N2G, hC, W2, b2, hA,
                           (unsigned*)SCR, (int*)(SCR + 100000), SCR + 200000,
                           rp, dinv, gh, bsum, stream);

  // hidden GEMM + global max over nodes
  hipMemsetAsync(maxed, 0, 1024 * sizeof(unsigned), stream);
  dim3 g(8, cdiv(N2G, NT));
  k_hidden_max<<<g, 256, 0, stream>>>(hA, Wh, bh, maxed, N2G);

  // classifier
  k_final<<<NCLS, 64, 0, stream>>>(maxed, Wl, bl, out);
}

// Round 10
// 546.772 us; speedup vs baseline: 1.0720x; 1.0720x over previous
//
#include <hip/hip_runtime.h>
#include <cstdint>
#include <cmath>

#define N0G 100000
#define N1G 25000
#define N2G 6250
#define E0G 1600000
#define E1G 400000
#define E2G 100000
#define KCH 6
#define NCLS 40
#define RPB 512            // rows per bucket (9 bits local row)
#define NBLK 240           // binning blocks
#define PAYB 17            // payload bits (col or edge idx < 131072)
#define SCT 16             // scan elems per thread
#define SCB (256 * SCT)    // scan elems per block

static inline int cdiv(long a, long b){ return (int)((a + b - 1) / b); }

// ================= deterministic bucket CSR build =================
// entry = (row & 511) << 17 | payload.  payload = col (graph) or edge idx (pool)

__global__ __launch_bounds__(256) void k_phist(const int* __restrict__ row, int E, int chunk,
                                               int* __restrict__ gh, int nbkt){
  __shared__ int h[256];
  for (int i = threadIdx.x; i < nbkt; i += 256) h[i] = 0;
  __syncthreads();
  int e0 = blockIdx.x * chunk, e1 = min(E, e0 + chunk);
  for (int e = e0 + threadIdx.x; e < e1; e += 256)
    atomicAdd(&h[row[e] >> 9], 1);
  __syncthreads();
  for (int i = threadIdx.x; i < nbkt; i += 256)
    gh[i * NBLK + blockIdx.x] = h[i];
}

// parallel flat exclusive scan of gh[M]: A) per-block sums, C) offset + local scan
__global__ __launch_bounds__(256) void k_scanA(const int* __restrict__ gh, int M, int* __restrict__ bsum){
  __shared__ int sh[256];
  int base = blockIdx.x * SCB + threadIdx.x * SCT;
  int s = 0;
#pragma unroll
  for (int j = 0; j < SCT; j++){ int i = base + j; if (i < M) s += gh[i]; }
  sh[threadIdx.x] = s; __syncthreads();
  for (int o = 128; o > 0; o >>= 1){
    if (threadIdx.x < o) sh[threadIdx.x] += sh[threadIdx.x + o];
    __syncthreads();
  }
  if (threadIdx.x == 0) bsum[blockIdx.x] = sh[0];
}

__global__ __launch_bounds__(256) void k_scanC(int* __restrict__ gh, int M, const int* __restrict__ bsum,
                                               int* __restrict__ rp, int N, int E){
  __shared__ int sh[256];
  __shared__ int blockoff;
  if (threadIdx.x == 0){
    int off = 0;
    for (int j = 0; j < (int)blockIdx.x; j++) off += bsum[j];
    blockoff = off;
  }
  int base = blockIdx.x * SCB + threadIdx.x * SCT;
  int v[SCT]; int s = 0;
#pragma unroll
  for (int j = 0; j < SCT; j++){ int i = base + j; v[j] = (i < M) ? gh[i] : 0; s += v[j]; }
  sh[threadIdx.x] = s;
  __syncthreads();
  for (int o = 1; o < 256; o <<= 1){
    int t = (threadIdx.x >= o) ? sh[threadIdx.x - o] : 0;
    __syncthreads();
    sh[threadIdx.x] += t;
    __syncthreads();
  }
  int excl = blockoff + sh[threadIdx.x] - s;
#pragma unroll
  for (int j = 0; j < SCT; j++){
    int i = base + j;
    if (i < M){ gh[i] = excl; excl += v[j]; }
  }
  if (blockIdx.x == 0 && threadIdx.x == 0) rp[N] = E;
}

template<bool POOL>
__global__ __launch_bounds__(256) void k_pscatter(const int* __restrict__ row, const int* __restrict__ col,
                                                  int E, int chunk, const int* __restrict__ gh,
                                                  unsigned* __restrict__ ebuf, int nbkt){
  __shared__ int cur[256];
  for (int i = threadIdx.x; i < nbkt; i += 256) cur[i] = gh[i * NBLK + blockIdx.x];
  __syncthreads();
  int e0 = blockIdx.x * chunk, e1 = min(E, e0 + chunk);
  for (int e = e0 + threadIdx.x; e < e1; e += 256){
    int r = row[e];
    int dst = atomicAdd(&cur[r >> 9], 1);
    unsigned pay = POOL ? (unsigned)e : (unsigned)col[e];
    ebuf[dst] = ((unsigned)(r & 511) << PAYB) | pay;
  }
}

template<bool POOL>
__global__ __launch_bounds__(512) void k_bfinal(const unsigned* __restrict__ ebuf,
                                                const int* __restrict__ gh, int nbkt, int N, int E,
                                                const int* __restrict__ pcol, const float* __restrict__ pval,
                                                int* __restrict__ rp, float* __restrict__ dinv,
                                                int* __restrict__ cs, float* __restrict__ wv){
  __shared__ int h[512];
  __shared__ int cur[512];
  int b = blockIdx.x;
  int e0 = gh[b * NBLK];
  int e1 = (b + 1 < nbkt) ? gh[(b + 1) * NBLK] : E;
  int r0 = b * RPB;
  int t = threadIdx.x;
  h[t] = 0;
  __syncthreads();
  for (int e = e0 + t; e < e1; e += 512)
    atomicAdd(&h[ebuf[e] >> PAYB], 1);
  __syncthreads();
  int cnt = h[t];
  __syncthreads();
  for (int o = 1; o < 512; o <<= 1){
    int tmp = (t >= o) ? h[t - o] : 0;
    __syncthreads();
    h[t] += tmp;
    __syncthreads();
  }
  int excl = h[t] - cnt;
  cur[t] = excl;
  if (r0 + t < N){
    rp[r0 + t] = e0 + excl;
    if (!POOL) dinv[r0 + t] = cnt > 0 ? rsqrtf((float)cnt) : 0.f;
  }
  __syncthreads();
  for (int e = e0 + t; e < e1; e += 512){
    unsigned u = ebuf[e];
    int p = atomicAdd(&cur[u >> PAYB], 1);
    int dst = e0 + p;
    if (POOL){
      int ei = (int)(u & ((1u << PAYB) - 1));
      cs[dst] = pcol[ei]; wv[dst] = pval[ei];
    } else {
      cs[dst] = (int)(u & ((1u << PAYB) - 1));
    }
  }
}

// ================= CSR gathers =================
__global__ __launch_bounds__(256) void k_gather3(const int* __restrict__ rp, const int* __restrict__ cs,
                          const float* __restrict__ src, const float* __restrict__ dinv,
                          const float* __restrict__ sub, float* __restrict__ dst,
                          int N, float scale){
  int n = blockIdx.x * blockDim.x + threadIdx.x;
  if (n >= N) return;
  int e0 = rp[n], e1 = rp[n + 1];
  float a0 = 0.f, a1 = 0.f, a2 = 0.f;
  for (int e = e0; e < e1; e++){
    int c = cs[e];
    float w = dinv[c];
    const float* sp = src + c * 3;
    a0 = fmaf(w, sp[0], a0);
    a1 = fmaf(w, sp[1], a1);
    a2 = fmaf(w, sp[2], a2);
  }
  float m = -scale * dinv[n];
  float r0 = m * a0, r1 = m * a1, r2 = m * a2;
  if (sub){ r0 -= sub[n * 3 + 0]; r1 -= sub[n * 3 + 1]; r2 -= sub[n * 3 + 2]; }
  dst[n * 3 + 0] = r0; dst[n * 3 + 1] = r1; dst[n * 3 + 2] = r2;
}

// F multiple of 4; lane-group of L=F/4 per node, float4 per lane.
template<int F>
__global__ __launch_bounds__(256) void k_gatherT(const int* __restrict__ rp, const int* __restrict__ cs,
                          const float* __restrict__ src, const float* __restrict__ dinv,
                          const float* __restrict__ sub, float* __restrict__ dst,
                          int N, float scale){
  constexpr int L = F / 4;
  int tid = blockIdx.x * 256 + threadIdx.x;
  int n = tid / L, q = tid % L;
  if (n >= N) return;
  const float4* src4 = (const float4*)src;
  int e0 = rp[n], e1 = rp[n + 1];
  float4 acc = make_float4(0.f, 0.f, 0.f, 0.f);
  for (int e = e0; e < e1; e++){
    int c = cs[e];
    float w = dinv[c];
    float4 v = src4[(long)c * L + q];
    acc.x = fmaf(w, v.x, acc.x); acc.y = fmaf(w, v.y, acc.y);
    acc.z = fmaf(w, v.z, acc.z); acc.w = fmaf(w, v.w, acc.w);
  }
  float m = -scale * dinv[n];
  float4 r = make_float4(m * acc.x, m * acc.y, m * acc.z, m * acc.w);
  if (sub){
    float4 sv = ((const float4*)sub)[(long)n * L + q];
    r.x -= sv.x; r.y -= sv.y; r.z -= sv.z; r.w -= sv.w;
  }
  ((float4*)dst)[(long)n * L + q] = r;
}

template<int F>
__global__ __launch_bounds__(256) void k_gatherP(const int* __restrict__ rp, const int* __restrict__ cs,
                          const float* __restrict__ wv, const float* __restrict__ h,
                          float* __restrict__ dst, int N){
  constexpr int L = F / 4;
  int tid = blockIdx.x * 256 + threadIdx.x;
  int n = tid / L, q = tid % L;
  if (n >= N) return;
  const float4* h4 = (const float4*)h;
  int e0 = rp[n], e1 = rp[n + 1];
  float4 acc = make_float4(0.f, 0.f, 0.f, 0.f);
  for (int e = e0; e < e1; e++){
    int c = cs[e];
    float w = wv[e];
    float4 v = h4[(long)c * L + q];
    acc.x = fmaf(w, v.x, acc.x); acc.y = fmaf(w, v.y, acc.y);
    acc.z = fmaf(w, v.z, acc.z); acc.w = fmaf(w, v.w, acc.w);
  }
  ((float4*)dst)[(long)n * L + q] = acc;
}

// ================= dense cheb contraction, LDS-tiled, hidden_max-shaped loop =================
// C[N, FO] = X6[N, 6F] @ W[6F, FO] + b.  Per f4-iter: 4 W float4 loads + R ds_read_b128 + 16R FMA.
template<int F, int FO, int R, bool RELU>
__global__ __launch_bounds__(256) void k_cheb_tile(const float* __restrict__ x, const float* __restrict__ T, int N,
                           const float* __restrict__ W, const float* __restrict__ b,
                           float* __restrict__ out){
  constexpr int OQ4  = FO / 4;
  constexpr int NSUB = 256 / OQ4;
  constexpr int NT   = NSUB * R;
  constexpr int F6   = KCH * F;
  int n0 = blockIdx.x * NT;
  int o4   = threadIdx.x % OQ4;
  int nsub = threadIdx.x / OQ4;
  const float4* W4 = (const float4*)W;       // [F6][OQ4]
  float4 acc[R];
  float4 bb = ((const float4*)b)[o4];
#pragma unroll
  for (int r = 0; r < R; r++) acc[r] = bb;

  if constexpr (F == 3){
    constexpr int PITCH = F6 + 2;            // 20 dwords: rows skew 20 banks; 8 addrs/wave -> 2-way (free)
    __shared__ float X[NT * PITCH];
    for (int i = threadIdx.x; i < NT * F6; i += 256){
      int k = i / (NT * 3);
      int idx = i - k * (NT * 3);            // node*3 + j
      const float* src = (k == 0) ? x : (T + (size_t)(k - 1) * N * 3);
      int node = idx / 3, j = idx - node * 3;
      float v = (n0 + node < N) ? src[(long)n0 * 3 + idx] : 0.f;
      X[node * PITCH + k * 3 + j] = v;
    }
    __syncthreads();
#pragma unroll
    for (int f = 0; f < F6; f++){
      float4 w = W4[(long)f * OQ4 + o4];
#pragma unroll
      for (int r = 0; r < R; r++){
        float v = X[(nsub * R + r) * PITCH + f];
        acc[r].x = fmaf(v, w.x, acc[r].x); acc[r].y = fmaf(v, w.y, acc[r].y);
        acc[r].z = fmaf(v, w.z, acc[r].z); acc[r].w = fmaf(v, w.w, acc[r].w);
      }
    }
  } else {
    constexpr int L  = F / 4;
    constexpr int P4 = F6 / 4 + 1;           // float4 pitch: rows skew 4 banks -> conflict-free b128
    __shared__ float4 X[NT * P4];
    for (int i = threadIdx.x; i < NT * KCH * L; i += 256){
      int k = i / (NT * L);
      int idx = i - k * (NT * L);            // node*L + q
      int node = idx / L, q = idx - node * L;
      const float4* src4 = (const float4*)((k == 0) ? x : (T + (size_t)(k - 1) * N * F));
      float4 v = make_float4(0.f, 0.f, 0.f, 0.f);
      if (n0 + node < N) v = src4[(long)n0 * L + idx];
      X[node * P4 + k * L + q] = v;
    }
    __syncthreads();
#pragma unroll 4
    for (int f4 = 0; f4 < F6 / 4; f4++){
      float4 w0 = W4[(long)(4 * f4 + 0) * OQ4 + o4];
      float4 w1 = W4[(long)(4 * f4 + 1) * OQ4 + o4];
      float4 w2 = W4[(long)(4 * f4 + 2) * OQ4 + o4];
      float4 w3 = W4[(long)(4 * f4 + 3) * OQ4 + o4];
#pragma unroll
      for (int r = 0; r < R; r++){
        float4 hv = X[(nsub * R + r) * P4 + f4];
        acc[r].x = fmaf(hv.x, w0.x, acc[r].x); acc[r].y = fmaf(hv.x, w0.y, acc[r].y);
        acc[r].z = fmaf(hv.x, w0.z, acc[r].z); acc[r].w = fmaf(hv.x, w0.w, acc[r].w);
        acc[r].x = fmaf(hv.y, w1.x, acc[r].x); acc[r].y = fmaf(hv.y, w1.y, acc[r].y);
        acc[r].z = fmaf(hv.y, w1.z, acc[r].z); acc[r].w = fmaf(hv.y, w1.w, acc[r].w);
        acc[r].x = fmaf(hv.z, w2.x, acc[r].x); acc[r].y = fmaf(hv.z, w2.y, acc[r].y);
        acc[r].z = fmaf(hv.z, w2.z, acc[r].z); acc[r].w = fmaf(hv.z, w2.w, acc[r].w);
        acc[r].x = fmaf(hv.w, w3.x, acc[r].x); acc[r].y = fmaf(hv.w, w3.y, acc[r].y);
        acc[r].z = fmaf(hv.w, w3.z, acc[r].z); acc[r].w = fmaf(hv.w, w3.w, acc[r].w);
      }
    }
  }

#pragma unroll
  for (int r = 0; r < R; r++){
    int n = n0 + nsub * R + r;
    if (n < N){
      float4 o = acc[r];
      if (RELU){
        o.x = fmaxf(o.x, 0.f); o.y = fmaxf(o.y, 0.f);
        o.z = fmaxf(o.z, 0.f); o.w = fmaxf(o.w, 0.f);
      }
      ((float4*)out)[(long)n * OQ4 + o4] = o;
    }
  }
}

// ================= final hidden GEMM + global max + classifier =================
__device__ __forceinline__ unsigned fmap(float x){
  unsigned u = __float_as_uint(x);
  return (u & 0x80000000u) ? ~u : (u | 0x80000000u);
}
__device__ __forceinline__ float funmap(unsigned u){
  return (u & 0x80000000u) ? __uint_as_float(u ^ 0x80000000u) : __uint_as_float(~u);
}

// grid (8, ceil(N/32)): block = 32 nodes x 128 outputs (32 float4).
// thread = 1 float4 output x 4 nodes (acc[4] = 16 VGPR). LDS tile [n][f4] 16 KB.
#define NT 32
__global__ __launch_bounds__(256) void k_hidden_max(const float* __restrict__ h2, const float* __restrict__ Wh,
                             const float* __restrict__ bh, unsigned* __restrict__ maxed, int N){
  __shared__ float4 sh4[NT * 32];        // 16 KB
  int n0 = blockIdx.y * NT;
  for (int i = threadIdx.x; i < NT * 32; i += 256){
    int n = i >> 5;
    float4 v = make_float4(0.f, 0.f, 0.f, 0.f);
    if (n0 + n < N) v = ((const float4*)h2)[(long)(n0 + n) * 32 + (i & 31)];
    sh4[i] = v;
  }
  __syncthreads();
  int o4l  = threadIdx.x & 31;           // o4 within tile
  int nsub = threadIdx.x >> 5;           // 0..7, 4 nodes each
  int o4   = blockIdx.x * 32 + o4l;      // global float4 output index
  const float4* Wh4 = (const float4*)Wh;
  float4 acc[4];
#pragma unroll
  for (int j = 0; j < 4; j++) acc[j] = make_float4(0.f, 0.f, 0.f, 0.f);
  for (int f4 = 0; f4 < 32; f4++){
    float4 w0 = Wh4[(long)(4 * f4 + 0) * 256 + o4];
    float4 w1 = Wh4[(long)(4 * f4 + 1) * 256 + o4];
    float4 w2 = Wh4[(long)(4 * f4 + 2) * 256 + o4];
    float4 w3 = Wh4[(long)(4 * f4 + 3) * 256 + o4];
#pragma unroll
    for (int j = 0; j < 4; j++){
      float4 hv = sh4[(nsub * 4 + j) * 32 + f4];
      acc[j].x = fmaf(hv.x, w0.x, acc[j].x); acc[j].y = fmaf(hv.x, w0.y, acc[j].y);
      acc[j].z = fmaf(hv.x, w0.z, acc[j].z); acc[j].w = fmaf(hv.x, w0.w, acc[j].w);
      acc[j].x = fmaf(hv.y, w1.x, acc[j].x); acc[j].y = fmaf(hv.y, w1.y, acc[j].y);
      acc[j].z = fmaf(hv.y, w1.z, acc[j].z); acc[j].w = fmaf(hv.y, w1.w, acc[j].w);
      acc[j].x = fmaf(hv.z, w2.x, acc[j].x); acc[j].y = fmaf(hv.z, w2.y, acc[j].y);
      acc[j].z = fmaf(hv.z, w2.z, acc[j].z); acc[j].w = fmaf(hv.z, w2.w, acc[j].w);
      acc[j].x = fmaf(hv.w, w3.x, acc[j].x); acc[j].y = fmaf(hv.w, w3.y, acc[j].y);
      acc[j].z = fmaf(hv.w, w3.z, acc[j].z); acc[j].w = fmaf(hv.w, w3.w, acc[j].w);
    }
  }
  float4 m = make_float4(-INFINITY, -INFINITY, -INFINITY, -INFINITY);
#pragma unroll
  for (int j = 0; j < 4; j++){
    if (n0 + nsub * 4 + j < N){
      m.x = fmaxf(m.x, acc[j].x); m.y = fmaxf(m.y, acc[j].y);
      m.z = fmaxf(m.z, acc[j].z); m.w = fmaxf(m.w, acc[j].w);
    }
  }
  __syncthreads();
  sh4[nsub * 32 + o4l] = m;
  __syncthreads();
  if (nsub == 0){
#pragma unroll
    for (int s = 1; s < 8; s++){
      float4 o = sh4[s * 32 + o4l];
      m.x = fmaxf(m.x, o.x); m.y = fmaxf(m.y, o.y);
      m.z = fmaxf(m.z, o.z); m.w = fmaxf(m.w, o.w);
    }
    float4 b4 = ((const float4*)bh)[o4];
    atomicMax(&maxed[4 * o4 + 0], fmap(m.x + b4.x));
    atomicMax(&maxed[4 * o4 + 1], fmap(m.y + b4.y));
    atomicMax(&maxed[4 * o4 + 2], fmap(m.z + b4.z));
    atomicMax(&maxed[4 * o4 + 3], fmap(m.w + b4.w));
  }
}

// 40 blocks (one per class) x 64 lanes; wave shuffle reduce.
__global__ __launch_bounds__(64) void k_final(const unsigned* __restrict__ maxed, const float* __restrict__ Wl,
                        const float* __restrict__ bl, float* __restrict__ out){
  int c = blockIdx.x;
  int l = threadIdx.x;
  float acc = 0.f;
  for (int o = l; o < 1024; o += 64)
    acc = fmaf(funmap(maxed[o]), Wl[o * NCLS + c], acc);
  for (int off = 32; off > 0; off >>= 1)
    acc += __shfl_down(acc, off);
  if (l == 0) out[c] = acc + bl[c];
}

// ================= drivers =================
static void run_scan(int* gh, int M, int* bsum, int* rp, int N, int E, hipStream_t s){
  int nb = cdiv(M, SCB);
  k_scanA<<<nb, 256, 0, s>>>(gh, M, bsum);
  k_scanC<<<nb, 256, 0, s>>>(gh, M, bsum, rp, N, E);
}

template<int F, int FO, int R, bool RELU>
static void run_cheb(const int* row, const int* col, int E, int N,
                     const float* x, const float* W, const float* b, float* out,
                     unsigned* ebuf, int* cs, float* T,
                     int* rp, float* dinv, int* gh, int* bsum, hipStream_t s){
  int nbkt = cdiv(N, RPB);
  int chunk = cdiv(E, NBLK);
  k_phist<<<NBLK, 256, 0, s>>>(row, E, chunk, gh, nbkt);
  run_scan(gh, nbkt * NBLK, bsum, rp, N, E, s);
  k_pscatter<false><<<NBLK, 256, 0, s>>>(row, col, E, chunk, gh, ebuf, nbkt);
  k_bfinal<false><<<nbkt, 512, 0, s>>>(ebuf, gh, nbkt, N, E, nullptr, nullptr, rp, dinv, cs, nullptr);

  const float* src = x; const float* sub = nullptr; float scale = 1.f;
  for (int k = 1; k < KCH; k++){
    float* Tk = T + (size_t)(k - 1) * N * F;
    if constexpr (F == 3)
      k_gather3<<<cdiv(N, 256), 256, 0, s>>>(rp, cs, src, dinv, sub, Tk, N, scale);
    else
      k_gatherT<F><<<cdiv((long)N * (F / 4), 256), 256, 0, s>>>(rp, cs, src, dinv, sub, Tk, N, scale);
    sub = src; src = Tk; scale = 2.f;
  }
  constexpr int NTC = (256 / (FO / 4)) * R;
  k_cheb_tile<F, FO, R, RELU><<<cdiv(N, NTC), 256, 0, s>>>(x, T, N, W, b, out);
}

template<int F>
static void run_pool(const int* row, const int* col, const float* val, int E, int Nout,
                     const float* h, float* out, unsigned* ebuf, int* cs, float* wv,
                     int* rp, int* gh, int* bsum, hipStream_t s){
  int nbkt = cdiv(Nout, RPB);
  int chunk = cdiv(E, NBLK);
  k_phist<<<NBLK, 256, 0, s>>>(row, E, chunk, gh, nbkt);
  run_scan(gh, nbkt * NBLK, bsum, rp, Nout, E, s);
  k_pscatter<true><<<NBLK, 256, 0, s>>>(row, col, E, chunk, gh, ebuf, nbkt);
  k_bfinal<true><<<nbkt, 512, 0, s>>>(ebuf, gh, nbkt, Nout, E, col, val, rp, nullptr, cs, wv);
  k_gatherP<F><<<cdiv((long)Nout * (F / 4), 256), 256, 0, s>>>(rp, cs, wv, h, out, Nout);
}

extern "C" void kernel_launch(void* const* d_in, const int* in_sizes, int n_in,
                              void* d_out, int out_size, void* d_ws, size_t ws_size,
                              hipStream_t stream){
  const float* pos = (const float*)d_in[0];
  const int*   ei0 = (const int*)d_in[1];
  const int*   ei1 = (const int*)d_in[2];
  const int*   ei2 = (const int*)d_in[3];
  const int*   p0r = (const int*)d_in[4];
  const int*   p0c = (const int*)d_in[5];
  const float* p0v = (const float*)d_in[6];
  const int*   p1r = (const int*)d_in[7];
  const int*   p1c = (const int*)d_in[8];
  const float* p1v = (const float*)d_in[9];
  const float* W0  = (const float*)d_in[10]; const float* b0 = (const float*)d_in[11];
  const float* W1  = (const float*)d_in[12]; const float* b1 = (const float*)d_in[13];
  const float* W2  = (const float*)d_in[14]; const float* b2 = (const float*)d_in[15];
  const float* Wh  = (const float*)d_in[16]; const float* bh = (const float*)d_in[17];
  const float* Wl  = (const float*)d_in[18]; const float* bl = (const float*)d_in[19];
  float* out = (float*)d_out;

  // workspace layout (float-sized units)
  float* SCR = (float*)d_ws;                 // 4.8M floats, per-stage overlays
  float* hA  = SCR + 4800000;                // 3.2M  (N0*32 / N2*128)
  float* hB  = hA + 3200000;                 // 1.6M  (N1*64)
  float* hC  = hB + 1600000;                 // 0.8M  (N1*32 / N2*64)
  int* rp     = (int*)(hC + 800000);         // 100001
  float* dinv = (float*)(rp + 100001);       // 100000
  int* gh     = (int*)(dinv + 100000);       // 47040 (196*240 max)
  int* bsum   = gh + 47040;                  // 16
  unsigned* maxed = (unsigned*)(bsum + 16);  // 1024

  // layer 0: cheb(pos) -> hA [N0,32], relu.  SCR: ebuf 1.6M | cs 1.6M | T 1.5M
  run_cheb<3, 32, 2, true>(ei0, ei0 + E0G, E0G, N0G, pos, W0, b0, hA,
                        (unsigned*)SCR, (int*)(SCR + 1600000), SCR + 3200000,
                        rp, dinv, gh, bsum, stream);

  // pool 0: hA -> hC [N1,32].  SCR: ebuf 100K | cs 100K | wv 100K
  run_pool<32>(p0r, p0c, p0v, N0G, N1G, hA, hC,
               (unsigned*)SCR, (int*)(SCR + 100000), SCR + 200000,
               rp, gh, bsum, stream);

  // layer 1: cheb(hC) -> hB [N1,64], relu.  SCR: ebuf 400K | cs 400K | T 4M
  run_cheb<32, 64, 2, true>(ei1, ei1 + E1G, E1G, N1G, hC, W1, b1, hB,
                         (unsigned*)SCR, (int*)(SCR + 400000), SCR + 800000,
                         rp, dinv, gh, bsum, stream);

  // pool 1: hB -> hC [N2,64].  SCR: ebuf 25K | cs 25K | wv 25K
  run_pool<64>(p1r, p1c, p1v, N1G, N2G, hB, hC,
               (unsigned*)SCR, (int*)(SCR + 25000), SCR + 50000,
               rp, gh, bsum, stream);

  // layer 2: cheb(hC) -> hA [N2,128], no relu.  SCR: ebuf 100K | cs 100K | T 2M
  run_cheb<64, 128, 2, false>(ei2, ei2 + E2G, E2G, N2G, hC, W2, b2, hA,
                           (unsigned*)SCR, (int*)(SCR + 100000), SCR + 200000,
                           rp, dinv, gh, bsum, stream);

  // hidden GEMM + global max over nodes
  hipMemsetAsync(maxed, 0, 1024 * sizeof(unsigned), stream);
  dim3 g(8, cdiv(N2G, NT));
  k_hidden_max<<<g, 256, 0, stream>>>(hA, Wh, bh, maxed, N2G);

  // classifier
  k_final<<<NCLS, 64, 0, stream>>>(maxed, Wl, bl, out);
}

// Round 11
// 466.577 us; speedup vs baseline: 1.2562x; 1.1719x over previous
//
#include <hip/hip_runtime.h>
#include <cstdint>
#include <cmath>

#define N0G 100000
#define N1G 25000
#define N2G 6250
#define E0G 1600000
#define E1G 400000
#define E2G 100000
#define KCH 6
#define NCLS 40
#define RPB 512            // rows per bucket (9 bits local row)
#define NBLK 240           // binning blocks
#define PAYB 17            // payload bits (col or edge idx < 131072)
#define SCT 16             // scan elems per thread
#define SCB (256 * SCT)    // scan elems per block

static inline int cdiv(long a, long b){ return (int)((a + b - 1) / b); }

// ================= deterministic bucket CSR build =================
__global__ __launch_bounds__(256) void k_phist(const int* __restrict__ row, int E, int chunk,
                                               int* __restrict__ gh, int nbkt){
  __shared__ int h[256];
  for (int i = threadIdx.x; i < nbkt; i += 256) h[i] = 0;
  __syncthreads();
  int e0 = blockIdx.x * chunk, e1 = min(E, e0 + chunk);
  for (int e = e0 + threadIdx.x; e < e1; e += 256)
    atomicAdd(&h[row[e] >> 9], 1);
  __syncthreads();
  for (int i = threadIdx.x; i < nbkt; i += 256)
    gh[i * NBLK + blockIdx.x] = h[i];
}

__global__ __launch_bounds__(256) void k_scanA(const int* __restrict__ gh, int M, int* __restrict__ bsum){
  __shared__ int sh[256];
  int base = blockIdx.x * SCB + threadIdx.x * SCT;
  int s = 0;
#pragma unroll
  for (int j = 0; j < SCT; j++){ int i = base + j; if (i < M) s += gh[i]; }
  sh[threadIdx.x] = s; __syncthreads();
  for (int o = 128; o > 0; o >>= 1){
    if (threadIdx.x < o) sh[threadIdx.x] += sh[threadIdx.x + o];
    __syncthreads();
  }
  if (threadIdx.x == 0) bsum[blockIdx.x] = sh[0];
}

__global__ __launch_bounds__(256) void k_scanC(int* __restrict__ gh, int M, const int* __restrict__ bsum,
                                               int* __restrict__ rp, int N, int E){
  __shared__ int sh[256];
  __shared__ int blockoff;
  if (threadIdx.x == 0){
    int off = 0;
    for (int j = 0; j < (int)blockIdx.x; j++) off += bsum[j];
    blockoff = off;
  }
  int base = blockIdx.x * SCB + threadIdx.x * SCT;
  int v[SCT]; int s = 0;
#pragma unroll
  for (int j = 0; j < SCT; j++){ int i = base + j; v[j] = (i < M) ? gh[i] : 0; s += v[j]; }
  sh[threadIdx.x] = s;
  __syncthreads();
  for (int o = 1; o < 256; o <<= 1){
    int t = (threadIdx.x >= o) ? sh[threadIdx.x - o] : 0;
    __syncthreads();
    sh[threadIdx.x] += t;
    __syncthreads();
  }
  int excl = blockoff + sh[threadIdx.x] - s;
#pragma unroll
  for (int j = 0; j < SCT; j++){
    int i = base + j;
    if (i < M){ gh[i] = excl; excl += v[j]; }
  }
  if (blockIdx.x == 0 && threadIdx.x == 0) rp[N] = E;
}

template<bool POOL>
__global__ __launch_bounds__(256) void k_pscatter(const int* __restrict__ row, const int* __restrict__ col,
                                                  int E, int chunk, const int* __restrict__ gh,
                                                  unsigned* __restrict__ ebuf, int nbkt){
  __shared__ int cur[256];
  for (int i = threadIdx.x; i < nbkt; i += 256) cur[i] = gh[i * NBLK + blockIdx.x];
  __syncthreads();
  int e0 = blockIdx.x * chunk, e1 = min(E, e0 + chunk);
  for (int e = e0 + threadIdx.x; e < e1; e += 256){
    int r = row[e];
    int dst = atomicAdd(&cur[r >> 9], 1);
    unsigned pay = POOL ? (unsigned)e : (unsigned)col[e];
    ebuf[dst] = ((unsigned)(r & 511) << PAYB) | pay;
  }
}

template<bool POOL>
__global__ __launch_bounds__(512) void k_bfinal(const unsigned* __restrict__ ebuf,
                                                const int* __restrict__ gh, int nbkt, int N, int E,
                                                const int* __restrict__ pcol, const float* __restrict__ pval,
                                                int* __restrict__ rp, float* __restrict__ dinv,
                                                int* __restrict__ cs, float* __restrict__ wv){
  __shared__ int h[512];
  __shared__ int cur[512];
  int b = blockIdx.x;
  int e0 = gh[b * NBLK];
  int e1 = (b + 1 < nbkt) ? gh[(b + 1) * NBLK] : E;
  int r0 = b * RPB;
  int t = threadIdx.x;
  h[t] = 0;
  __syncthreads();
  for (int e = e0 + t; e < e1; e += 512)
    atomicAdd(&h[ebuf[e] >> PAYB], 1);
  __syncthreads();
  int cnt = h[t];
  __syncthreads();
  for (int o = 1; o < 512; o <<= 1){
    int tmp = (t >= o) ? h[t - o] : 0;
    __syncthreads();
    h[t] += tmp;
    __syncthreads();
  }
  int excl = h[t] - cnt;
  cur[t] = excl;
  if (r0 + t < N){
    rp[r0 + t] = e0 + excl;
    if (!POOL) dinv[r0 + t] = cnt > 0 ? rsqrtf((float)cnt) : 0.f;
  }
  __syncthreads();
  for (int e = e0 + t; e < e1; e += 512){
    unsigned u = ebuf[e];
    int p = atomicAdd(&cur[u >> PAYB], 1);
    int dst = e0 + p;
    if (POOL){
      int ei = (int)(u & ((1u << PAYB) - 1));
      cs[dst] = pcol[ei]; wv[dst] = pval[ei];
    } else {
      cs[dst] = (int)(u & ((1u << PAYB) - 1));
    }
  }
}

// ================= prescale: xs[n] = dinv[n] * src[n] =================
__global__ __launch_bounds__(256) void k_prescale3(const float* __restrict__ x, const float* __restrict__ dinv,
                                                   float4* __restrict__ xs, int N){
  int n = blockIdx.x * 256 + threadIdx.x;
  if (n >= N) return;
  float d = dinv[n];
  xs[n] = make_float4(d * x[n * 3 + 0], d * x[n * 3 + 1], d * x[n * 3 + 2], 0.f);
}

template<int F>
__global__ __launch_bounds__(256) void k_prescaleF(const float* __restrict__ x, const float* __restrict__ dinv,
                                                   float4* __restrict__ xs, int N){
  constexpr int L = F / 4;
  int i = blockIdx.x * 256 + threadIdx.x;
  if (i >= N * L) return;
  float d = dinv[i / L];
  float4 v = ((const float4*)x)[i];
  xs[i] = make_float4(d * v.x, d * v.y, d * v.z, d * v.w);
}

// ================= CSR gathers (prescaled source, edge-split lanes) =================
// 4 lanes per node; each handles every 4th edge; shfl_xor reduce.
__global__ __launch_bounds__(256) void k_gather3(const int* __restrict__ rp, const int* __restrict__ cs,
                          const float4* __restrict__ xs, const float* __restrict__ dinv,
                          const float* __restrict__ sub, float* __restrict__ dst,
                          float4* __restrict__ xs_out, int N, float scale){
  int tid = blockIdx.x * 256 + threadIdx.x;
  int n = tid >> 2, q = tid & 3;
  if (n >= N) return;
  int e0 = rp[n], e1 = rp[n + 1];
  float a0 = 0.f, a1 = 0.f, a2 = 0.f;
  for (int e = e0 + q; e < e1; e += 4){
    float4 v = xs[cs[e]];
    a0 += v.x; a1 += v.y; a2 += v.z;
  }
  a0 += __shfl_xor(a0, 1); a1 += __shfl_xor(a1, 1); a2 += __shfl_xor(a2, 1);
  a0 += __shfl_xor(a0, 2); a1 += __shfl_xor(a1, 2); a2 += __shfl_xor(a2, 2);
  if (q == 0){
    float dn = dinv[n];
    float m = -scale * dn;
    float r0 = m * a0, r1 = m * a1, r2 = m * a2;
    if (sub){ r0 -= sub[n * 3 + 0]; r1 -= sub[n * 3 + 1]; r2 -= sub[n * 3 + 2]; }
    dst[n * 3 + 0] = r0; dst[n * 3 + 1] = r1; dst[n * 3 + 2] = r2;
    if (xs_out) xs_out[n] = make_float4(dn * r0, dn * r1, dn * r2, 0.f);
  }
}

// G = 2L lanes per node: f4 = q%L, edge-split es = q/L; one shfl_xor(L) reduce.
template<int F>
__global__ __launch_bounds__(256) void k_gatherT(const int* __restrict__ rp, const int* __restrict__ cs,
                          const float4* __restrict__ xs, const float* __restrict__ dinv,
                          const float* __restrict__ sub, float* __restrict__ dst,
                          float4* __restrict__ xs_out, int N, float scale){
  constexpr int L = F / 4;
  constexpr int G = 2 * L;
  int tid = blockIdx.x * 256 + threadIdx.x;
  int n = tid / G, q = tid % G;
  if (n >= N) return;
  int f4 = q % L, es = q / L;
  int e0 = rp[n], e1 = rp[n + 1];
  float4 acc = make_float4(0.f, 0.f, 0.f, 0.f);
  for (int e = e0 + es; e < e1; e += 2){
    float4 v = xs[(long)cs[e] * L + f4];
    acc.x += v.x; acc.y += v.y; acc.z += v.z; acc.w += v.w;
  }
  acc.x += __shfl_xor(acc.x, L); acc.y += __shfl_xor(acc.y, L);
  acc.z += __shfl_xor(acc.z, L); acc.w += __shfl_xor(acc.w, L);
  if (es == 0){
    float dn = dinv[n];
    float m = -scale * dn;
    float4 r = make_float4(m * acc.x, m * acc.y, m * acc.z, m * acc.w);
    if (sub){
      float4 sv = ((const float4*)sub)[(long)n * L + f4];
      r.x -= sv.x; r.y -= sv.y; r.z -= sv.z; r.w -= sv.w;
    }
    ((float4*)dst)[(long)n * L + f4] = r;
    if (xs_out) xs_out[(long)n * L + f4] = make_float4(dn * r.x, dn * r.y, dn * r.z, dn * r.w);
  }
}

template<int F>
__global__ __launch_bounds__(256) void k_gatherP(const int* __restrict__ rp, const int* __restrict__ cs,
                          const float* __restrict__ wv, const float* __restrict__ h,
                          float* __restrict__ dst, int N){
  constexpr int L = F / 4;
  int tid = blockIdx.x * 256 + threadIdx.x;
  int n = tid / L, q = tid % L;
  if (n >= N) return;
  const float4* h4 = (const float4*)h;
  int e0 = rp[n], e1 = rp[n + 1];
  float4 acc = make_float4(0.f, 0.f, 0.f, 0.f);
  for (int e = e0; e < e1; e++){
    int c = cs[e];
    float w = wv[e];
    float4 v = h4[(long)c * L + q];
    acc.x = fmaf(w, v.x, acc.x); acc.y = fmaf(w, v.y, acc.y);
    acc.z = fmaf(w, v.z, acc.z); acc.w = fmaf(w, v.w, acc.w);
  }
  ((float4*)dst)[(long)n * L + q] = acc;
}

// ================= dense cheb contraction, LDS-tiled =================
template<int F, int FO, int R, bool RELU>
__global__ __launch_bounds__(256) void k_cheb_tile(const float* __restrict__ x, const float* __restrict__ T, int N,
                           const float* __restrict__ W, const float* __restrict__ b,
                           float* __restrict__ out){
  constexpr int OQ4  = FO / 4;
  constexpr int NSUB = 256 / OQ4;
  constexpr int NT   = NSUB * R;
  constexpr int F6   = KCH * F;
  int n0 = blockIdx.x * NT;
  int o4   = threadIdx.x % OQ4;
  int nsub = threadIdx.x / OQ4;
  const float4* W4 = (const float4*)W;       // [F6][OQ4]
  float4 acc[R];
  float4 bb = ((const float4*)b)[o4];
#pragma unroll
  for (int r = 0; r < R; r++) acc[r] = bb;

  if constexpr (F == 3){
    constexpr int PITCH = F6 + 2;
    __shared__ float X[NT * PITCH];
    for (int i = threadIdx.x; i < NT * F6; i += 256){
      int k = i / (NT * 3);
      int idx = i - k * (NT * 3);
      const float* src = (k == 0) ? x : (T + (size_t)(k - 1) * N * 3);
      int node = idx / 3, j = idx - node * 3;
      float v = (n0 + node < N) ? src[(long)n0 * 3 + idx] : 0.f;
      X[node * PITCH + k * 3 + j] = v;
    }
    __syncthreads();
#pragma unroll
    for (int f = 0; f < F6; f++){
      float4 w = W4[(long)f * OQ4 + o4];
#pragma unroll
      for (int r = 0; r < R; r++){
        float v = X[(nsub * R + r) * PITCH + f];
        acc[r].x = fmaf(v, w.x, acc[r].x); acc[r].y = fmaf(v, w.y, acc[r].y);
        acc[r].z = fmaf(v, w.z, acc[r].z); acc[r].w = fmaf(v, w.w, acc[r].w);
      }
    }
  } else {
    constexpr int L  = F / 4;
    constexpr int P4 = F6 / 4 + 1;
    __shared__ float4 X[NT * P4];
    for (int i = threadIdx.x; i < NT * KCH * L; i += 256){
      int k = i / (NT * L);
      int idx = i - k * (NT * L);
      int node = idx / L, q = idx - node * L;
      const float4* src4 = (const float4*)((k == 0) ? x : (T + (size_t)(k - 1) * N * F));
      float4 v = make_float4(0.f, 0.f, 0.f, 0.f);
      if (n0 + node < N) v = src4[(long)n0 * L + idx];
      X[node * P4 + k * L + q] = v;
    }
    __syncthreads();
#pragma unroll 4
    for (int f4 = 0; f4 < F6 / 4; f4++){
      float4 w0 = W4[(long)(4 * f4 + 0) * OQ4 + o4];
      float4 w1 = W4[(long)(4 * f4 + 1) * OQ4 + o4];
      float4 w2 = W4[(long)(4 * f4 + 2) * OQ4 + o4];
      float4 w3 = W4[(long)(4 * f4 + 3) * OQ4 + o4];
#pragma unroll
      for (int r = 0; r < R; r++){
        float4 hv = X[(nsub * R + r) * P4 + f4];
        acc[r].x = fmaf(hv.x, w0.x, acc[r].x); acc[r].y = fmaf(hv.x, w0.y, acc[r].y);
        acc[r].z = fmaf(hv.x, w0.z, acc[r].z); acc[r].w = fmaf(hv.x, w0.w, acc[r].w);
        acc[r].x = fmaf(hv.y, w1.x, acc[r].x); acc[r].y = fmaf(hv.y, w1.y, acc[r].y);
        acc[r].z = fmaf(hv.y, w1.z, acc[r].z); acc[r].w = fmaf(hv.y, w1.w, acc[r].w);
        acc[r].x = fmaf(hv.z, w2.x, acc[r].x); acc[r].y = fmaf(hv.z, w2.y, acc[r].y);
        acc[r].z = fmaf(hv.z, w2.z, acc[r].z); acc[r].w = fmaf(hv.z, w2.w, acc[r].w);
        acc[r].x = fmaf(hv.w, w3.x, acc[r].x); acc[r].y = fmaf(hv.w, w3.y, acc[r].y);
        acc[r].z = fmaf(hv.w, w3.z, acc[r].z); acc[r].w = fmaf(hv.w, w3.w, acc[r].w);
      }
    }
  }

#pragma unroll
  for (int r = 0; r < R; r++){
    int n = n0 + nsub * R + r;
    if (n < N){
      float4 o = acc[r];
      if (RELU){
        o.x = fmaxf(o.x, 0.f); o.y = fmaxf(o.y, 0.f);
        o.z = fmaxf(o.z, 0.f); o.w = fmaxf(o.w, 0.f);
      }
      ((float4*)out)[(long)n * OQ4 + o4] = o;
    }
  }
}

// ================= final hidden GEMM + global max + classifier =================
__device__ __forceinline__ unsigned fmap(float x){
  unsigned u = __float_as_uint(x);
  return (u & 0x80000000u) ? ~u : (u | 0x80000000u);
}
__device__ __forceinline__ float funmap(unsigned u){
  return (u & 0x80000000u) ? __uint_as_float(u ^ 0x80000000u) : __uint_as_float(~u);
}

#define NT 32
__global__ __launch_bounds__(256) void k_hidden_max(const float* __restrict__ h2, const float* __restrict__ Wh,
                             const float* __restrict__ bh, unsigned* __restrict__ maxed, int N){
  __shared__ float4 sh4[NT * 32];        // 16 KB
  int n0 = blockIdx.y * NT;
  for (int i = threadIdx.x; i < NT * 32; i += 256){
    int n = i >> 5;
    float4 v = make_float4(0.f, 0.f, 0.f, 0.f);
    if (n0 + n < N) v = ((const float4*)h2)[(long)(n0 + n) * 32 + (i & 31)];
    sh4[i] = v;
  }
  __syncthreads();
  int o4l  = threadIdx.x & 31;
  int nsub = threadIdx.x >> 5;
  int o4   = blockIdx.x * 32 + o4l;
  const float4* Wh4 = (const float4*)Wh;
  float4 acc[4];
#pragma unroll
  for (int j = 0; j < 4; j++) acc[j] = make_float4(0.f, 0.f, 0.f, 0.f);
  for (int f4 = 0; f4 < 32; f4++){
    float4 w0 = Wh4[(long)(4 * f4 + 0) * 256 + o4];
    float4 w1 = Wh4[(long)(4 * f4 + 1) * 256 + o4];
    float4 w2 = Wh4[(long)(4 * f4 + 2) * 256 + o4];
    float4 w3 = Wh4[(long)(4 * f4 + 3) * 256 + o4];
#pragma unroll
    for (int j = 0; j < 4; j++){
      float4 hv = sh4[(nsub * 4 + j) * 32 + f4];
      acc[j].x = fmaf(hv.x, w0.x, acc[j].x); acc[j].y = fmaf(hv.x, w0.y, acc[j].y);
      acc[j].z = fmaf(hv.x, w0.z, acc[j].z); acc[j].w = fmaf(hv.x, w0.w, acc[j].w);
      acc[j].x = fmaf(hv.y, w1.x, acc[j].x); acc[j].y = fmaf(hv.y, w1.y, acc[j].y);
      acc[j].z = fmaf(hv.y, w1.z, acc[j].z); acc[j].w = fmaf(hv.y, w1.w, acc[j].w);
      acc[j].x = fmaf(hv.z, w2.x, acc[j].x); acc[j].y = fmaf(hv.z, w2.y, acc[j].y);
      acc[j].z = fmaf(hv.z, w2.z, acc[j].z); acc[j].w = fmaf(hv.z, w2.w, acc[j].w);
      acc[j].x = fmaf(hv.w, w3.x, acc[j].x); acc[j].y = fmaf(hv.w, w3.y, acc[j].y);
      acc[j].z = fmaf(hv.w, w3.z, acc[j].z); acc[j].w = fmaf(hv.w, w3.w, acc[j].w);
    }
  }
  float4 m = make_float4(-INFINITY, -INFINITY, -INFINITY, -INFINITY);
#pragma unroll
  for (int j = 0; j < 4; j++){
    if (n0 + nsub * 4 + j < N){
      m.x = fmaxf(m.x, acc[j].x); m.y = fmaxf(m.y, acc[j].y);
      m.z = fmaxf(m.z, acc[j].z); m.w = fmaxf(m.w, acc[j].w);
    }
  }
  __syncthreads();
  sh4[nsub * 32 + o4l] = m;
  __syncthreads();
  if (nsub == 0){
#pragma unroll
    for (int s = 1; s < 8; s++){
      float4 o = sh4[s * 32 + o4l];
      m.x = fmaxf(m.x, o.x); m.y = fmaxf(m.y, o.y);
      m.z = fmaxf(m.z, o.z); m.w = fmaxf(m.w, o.w);
    }
    float4 b4 = ((const float4*)bh)[o4];
    atomicMax(&maxed[4 * o4 + 0], fmap(m.x + b4.x));
    atomicMax(&maxed[4 * o4 + 1], fmap(m.y + b4.y));
    atomicMax(&maxed[4 * o4 + 2], fmap(m.z + b4.z));
    atomicMax(&maxed[4 * o4 + 3], fmap(m.w + b4.w));
  }
}

__global__ __launch_bounds__(64) void k_final(const unsigned* __restrict__ maxed, const float* __restrict__ Wl,
                        const float* __restrict__ bl, float* __restrict__ out){
  int c = blockIdx.x;
  int l = threadIdx.x;
  float acc = 0.f;
  for (int o = l; o < 1024; o += 64)
    acc = fmaf(funmap(maxed[o]), Wl[o * NCLS + c], acc);
  for (int off = 32; off > 0; off >>= 1)
    acc += __shfl_down(acc, off);
  if (l == 0) out[c] = acc + bl[c];
}

// ================= drivers =================
static void run_scan(int* gh, int M, int* bsum, int* rp, int N, int E, hipStream_t s){
  int nb = cdiv(M, SCB);
  k_scanA<<<nb, 256, 0, s>>>(gh, M, bsum);
  k_scanC<<<nb, 256, 0, s>>>(gh, M, bsum, rp, N, E);
}

template<int F, int FO, int R, bool RELU>
static void run_cheb(const int* row, const int* col, int E, int N,
                     const float* x, const float* W, const float* b, float* out,
                     unsigned* ebuf, int* cs, float* T, float4* xsA, float4* xsB,
                     int* rp, float* dinv, int* gh, int* bsum, hipStream_t s){
  int nbkt = cdiv(N, RPB);
  int chunk = cdiv(E, NBLK);
  k_phist<<<NBLK, 256, 0, s>>>(row, E, chunk, gh, nbkt);
  run_scan(gh, nbkt * NBLK, bsum, rp, N, E, s);
  k_pscatter<false><<<NBLK, 256, 0, s>>>(row, col, E, chunk, gh, ebuf, nbkt);
  k_bfinal<false><<<nbkt, 512, 0, s>>>(ebuf, gh, nbkt, N, E, nullptr, nullptr, rp, dinv, cs, nullptr);

  // prescale first source
  if constexpr (F == 3)
    k_prescale3<<<cdiv(N, 256), 256, 0, s>>>(x, dinv, xsA, N);
  else
    k_prescaleF<F><<<cdiv((long)N * (F / 4), 256), 256, 0, s>>>(x, dinv, xsA, N);

  const float* sub = nullptr; float scale = 1.f;
  float4* xin = xsA; float4* xout = xsB;
  const float* srcRaw = x;
  for (int k = 1; k < KCH; k++){
    float* Tk = T + (size_t)(k - 1) * N * F;
    float4* xo = (k == KCH - 1) ? nullptr : xout;
    if constexpr (F == 3)
      k_gather3<<<cdiv((long)N * 4, 256), 256, 0, s>>>(rp, cs, xin, dinv, sub, Tk, xo, N, scale);
    else
      k_gatherT<F><<<cdiv((long)N * (F / 2), 256), 256, 0, s>>>(rp, cs, xin, dinv, sub, Tk, xo, N, scale);
    sub = srcRaw; srcRaw = Tk; scale = 2.f;
    float4* t = xin; xin = xout; xout = t;
  }
  constexpr int NTC = (256 / (FO / 4)) * R;
  k_cheb_tile<F, FO, R, RELU><<<cdiv(N, NTC), 256, 0, s>>>(x, T, N, W, b, out);
}

template<int F>
static void run_pool(const int* row, const int* col, const float* val, int E, int Nout,
                     const float* h, float* out, unsigned* ebuf, int* cs, float* wv,
                     int* rp, int* gh, int* bsum, hipStream_t s){
  int nbkt = cdiv(Nout, RPB);
  int chunk = cdiv(E, NBLK);
  k_phist<<<NBLK, 256, 0, s>>>(row, E, chunk, gh, nbkt);
  run_scan(gh, nbkt * NBLK, bsum, rp, Nout, E, s);
  k_pscatter<true><<<NBLK, 256, 0, s>>>(row, col, E, chunk, gh, ebuf, nbkt);
  k_bfinal<true><<<nbkt, 512, 0, s>>>(ebuf, gh, nbkt, Nout, E, col, val, rp, nullptr, cs, wv);
  k_gatherP<F><<<cdiv((long)Nout * (F / 4), 256), 256, 0, s>>>(rp, cs, wv, h, out, Nout);
}

extern "C" void kernel_launch(void* const* d_in, const int* in_sizes, int n_in,
                              void* d_out, int out_size, void* d_ws, size_t ws_size,
                              hipStream_t stream){
  const float* pos = (const float*)d_in[0];
  const int*   ei0 = (const int*)d_in[1];
  const int*   ei1 = (const int*)d_in[2];
  const int*   ei2 = (const int*)d_in[3];
  const int*   p0r = (const int*)d_in[4];
  const int*   p0c = (const int*)d_in[5];
  const float* p0v = (const float*)d_in[6];
  const int*   p1r = (const int*)d_in[7];
  const int*   p1c = (const int*)d_in[8];
  const float* p1v = (const float*)d_in[9];
  const float* W0  = (const float*)d_in[10]; const float* b0 = (const float*)d_in[11];
  const float* W1  = (const float*)d_in[12]; const float* b1 = (const float*)d_in[13];
  const float* W2  = (const float*)d_in[14]; const float* b2 = (const float*)d_in[15];
  const float* Wh  = (const float*)d_in[16]; const float* bh = (const float*)d_in[17];
  const float* Wl  = (const float*)d_in[18]; const float* bl = (const float*)d_in[19];
  float* out = (float*)d_out;

  // workspace layout (float-sized units)
  float* SCR = (float*)d_ws;                 // 4.8M floats, per-stage overlays
  float* hA  = SCR + 4800000;                // 3.2M  (N0*32 / N2*128; L1 xs ping-pong)
  float* hB  = hA + 3200000;                 // 1.6M  (N1*64; L0 xs ping-pong)
  float* hC  = hB + 1600000;                 // 0.8M  (N1*32 / N2*64)
  int* rp     = (int*)(hC + 800000);         // 100001
  float* dinv = (float*)(rp + 100001);       // 100000
  int* gh     = (int*)(dinv + 100000);       // 47040 (196*240 max)
  int* bsum   = gh + 47040;                  // 16
  unsigned* maxed = (unsigned*)(bsum + 16);  // 1024

  // layer 0: cheb(pos) -> hA [N0,32], relu.
  // SCR: ebuf 1.6M | cs 1.6M | T 1.5M.  xs ping-pong (N0*4 x2 = 800K) in hB.
  run_cheb<3, 32, 2, true>(ei0, ei0 + E0G, E0G, N0G, pos, W0, b0, hA,
                        (unsigned*)SCR, (int*)(SCR + 1600000), SCR + 3200000,
                        (float4*)hB, (float4*)(hB + 400000),
                        rp, dinv, gh, bsum, stream);

  // pool 0: hA -> hC [N1,32].  SCR: ebuf 100K | cs 100K | wv 100K
  run_pool<32>(p0r, p0c, p0v, N0G, N1G, hA, hC,
               (unsigned*)SCR, (int*)(SCR + 100000), SCR + 200000,
               rp, gh, bsum, stream);

  // layer 1: cheb(hC) -> hB [N1,64], relu.
  // SCR: ebuf 400K | cs 400K | T 4M.  xs ping-pong (N1*32 x2 = 1.6M) in hA (free).
  run_cheb<32, 64, 2, true>(ei1, ei1 + E1G, E1G, N1G, hC, W1, b1, hB,
                         (unsigned*)SCR, (int*)(SCR + 400000), SCR + 800000,
                         (float4*)hA, (float4*)(hA + 800000),
                         rp, dinv, gh, bsum, stream);

  // pool 1: hB -> hC [N2,64].  SCR: ebuf 25K | cs 25K | wv 25K
  run_pool<64>(p1r, p1c, p1v, N1G, N2G, hB, hC,
               (unsigned*)SCR, (int*)(SCR + 25000), SCR + 50000,
               rp, gh, bsum, stream);

  // layer 2: cheb(hC) -> hA [N2,128], no relu.
  // SCR: ebuf 100K | cs 100K | T 2M (ends 2.2M).  xs ping-pong (N2*64 x2 = 800K) at SCR+2.2M.
  run_cheb<64, 128, 2, false>(ei2, ei2 + E2G, E2G, N2G, hC, W2, b2, hA,
                           (unsigned*)SCR, (int*)(SCR + 100000), SCR + 200000,
                           (float4*)(SCR + 2200000), (float4*)(SCR + 2600000),
                           rp, dinv, gh, bsum, stream);

  // hidden GEMM + global max over nodes
  hipMemsetAsync(maxed, 0, 1024 * sizeof(unsigned), stream);
  dim3 g(8, cdiv(N2G, NT));
  k_hidden_max<<<g, 256, 0, stream>>>(hA, Wh, bh, maxed, N2G);

  // classifier
  k_final<<<NCLS, 64, 0, stream>>>(maxed, Wl, bl, out);
}

// Round 12
// 453.713 us; speedup vs baseline: 1.2919x; 1.0284x over previous
//
#include <hip/hip_runtime.h>
#include <cstdint>
#include <cmath>

#define N0G 100000
#define N1G 25000
#define N2G 6250
#define E0G 1600000
#define E1G 400000
#define E2G 100000
#define KCH 6
#define NCLS 40
#define RPB 512            // rows per bucket (9 bits local row)
#define NBLK 240           // binning blocks
#define PAYB 17            // payload bits (col or edge idx < 131072)
#define SCT 16             // scan elems per thread
#define SCB (256 * SCT)    // scan elems per block

static inline int cdiv(long a, long b){ return (int)((a + b - 1) / b); }

// ================= deterministic bucket CSR build =================
__global__ __launch_bounds__(256) void k_phist(const int* __restrict__ row, int E, int chunk,
                                               int* __restrict__ gh, int nbkt){
  __shared__ int h[256];
  for (int i = threadIdx.x; i < nbkt; i += 256) h[i] = 0;
  __syncthreads();
  int e0 = blockIdx.x * chunk, e1 = min(E, e0 + chunk);
  for (int e = e0 + threadIdx.x; e < e1; e += 256)
    atomicAdd(&h[row[e] >> 9], 1);
  __syncthreads();
  for (int i = threadIdx.x; i < nbkt; i += 256)
    gh[i * NBLK + blockIdx.x] = h[i];
}

__global__ __launch_bounds__(256) void k_scanA(const int* __restrict__ gh, int M, int* __restrict__ bsum){
  __shared__ int sh[256];
  int base = blockIdx.x * SCB + threadIdx.x * SCT;
  int s = 0;
#pragma unroll
  for (int j = 0; j < SCT; j++){ int i = base + j; if (i < M) s += gh[i]; }
  sh[threadIdx.x] = s; __syncthreads();
  for (int o = 128; o > 0; o >>= 1){
    if (threadIdx.x < o) sh[threadIdx.x] += sh[threadIdx.x + o];
    __syncthreads();
  }
  if (threadIdx.x == 0) bsum[blockIdx.x] = sh[0];
}

__global__ __launch_bounds__(256) void k_scanC(int* __restrict__ gh, int M, const int* __restrict__ bsum,
                                               int* __restrict__ rp, int N, int E){
  __shared__ int sh[256];
  __shared__ int blockoff;
  if (threadIdx.x == 0){
    int off = 0;
    for (int j = 0; j < (int)blockIdx.x; j++) off += bsum[j];
    blockoff = off;
  }
  int base = blockIdx.x * SCB + threadIdx.x * SCT;
  int v[SCT]; int s = 0;
#pragma unroll
  for (int j = 0; j < SCT; j++){ int i = base + j; v[j] = (i < M) ? gh[i] : 0; s += v[j]; }
  sh[threadIdx.x] = s;
  __syncthreads();
  for (int o = 1; o < 256; o <<= 1){
    int t = (threadIdx.x >= o) ? sh[threadIdx.x - o] : 0;
    __syncthreads();
    sh[threadIdx.x] += t;
    __syncthreads();
  }
  int excl = blockoff + sh[threadIdx.x] - s;
#pragma unroll
  for (int j = 0; j < SCT; j++){
    int i = base + j;
    if (i < M){ gh[i] = excl; excl += v[j]; }
  }
  if (blockIdx.x == 0 && threadIdx.x == 0) rp[N] = E;
}

template<bool POOL>
__global__ __launch_bounds__(256) void k_pscatter(const int* __restrict__ row, const int* __restrict__ col,
                                                  int E, int chunk, const int* __restrict__ gh,
                                                  unsigned* __restrict__ ebuf, int nbkt){
  __shared__ int cur[256];
  for (int i = threadIdx.x; i < nbkt; i += 256) cur[i] = gh[i * NBLK + blockIdx.x];
  __syncthreads();
  int e0 = blockIdx.x * chunk, e1 = min(E, e0 + chunk);
  for (int e = e0 + threadIdx.x; e < e1; e += 256){
    int r = row[e];
    int dst = atomicAdd(&cur[r >> 9], 1);
    unsigned pay = POOL ? (unsigned)e : (unsigned)col[e];
    ebuf[dst] = ((unsigned)(r & 511) << PAYB) | pay;
  }
}

template<bool POOL>
__global__ __launch_bounds__(512) void k_bfinal(const unsigned* __restrict__ ebuf,
                                                const int* __restrict__ gh, int nbkt, int N, int E,
                                                const int* __restrict__ pcol, const float* __restrict__ pval,
                                                int* __restrict__ rp, float* __restrict__ dinv,
                                                int* __restrict__ cs, float* __restrict__ wv){
  __shared__ int h[512];
  __shared__ int cur[512];
  int b = blockIdx.x;
  int e0 = gh[b * NBLK];
  int e1 = (b + 1 < nbkt) ? gh[(b + 1) * NBLK] : E;
  int r0 = b * RPB;
  int t = threadIdx.x;
  h[t] = 0;
  __syncthreads();
  for (int e = e0 + t; e < e1; e += 512)
    atomicAdd(&h[ebuf[e] >> PAYB], 1);
  __syncthreads();
  int cnt = h[t];
  __syncthreads();
  for (int o = 1; o < 512; o <<= 1){
    int tmp = (t >= o) ? h[t - o] : 0;
    __syncthreads();
    h[t] += tmp;
    __syncthreads();
  }
  int excl = h[t] - cnt;
  cur[t] = excl;
  if (r0 + t < N){
    rp[r0 + t] = e0 + excl;
    if (!POOL) dinv[r0 + t] = cnt > 0 ? rsqrtf((float)cnt) : 0.f;
  }
  __syncthreads();
  for (int e = e0 + t; e < e1; e += 512){
    unsigned u = ebuf[e];
    int p = atomicAdd(&cur[u >> PAYB], 1);
    int dst = e0 + p;
    if (POOL){
      int ei = (int)(u & ((1u << PAYB) - 1));
      cs[dst] = pcol[ei]; wv[dst] = pval[ei];
    } else {
      cs[dst] = (int)(u & ((1u << PAYB) - 1));
    }
  }
}

// ================= prescale: xs[n] = dinv[n] * src[n] =================
__global__ __launch_bounds__(256) void k_prescale3(const float* __restrict__ x, const float* __restrict__ dinv,
                                                   float4* __restrict__ xs, int N){
  int n = blockIdx.x * 256 + threadIdx.x;
  if (n >= N) return;
  float d = dinv[n];
  xs[n] = make_float4(d * x[n * 3 + 0], d * x[n * 3 + 1], d * x[n * 3 + 2], 0.f);
}

template<int F>
__global__ __launch_bounds__(256) void k_prescaleF(const float* __restrict__ x, const float* __restrict__ dinv,
                                                   float4* __restrict__ xs, int N){
  constexpr int L = F / 4;
  int i = blockIdx.x * 256 + threadIdx.x;
  if (i >= N * L) return;
  float d = dinv[i / L];
  float4 v = ((const float4*)x)[i];
  xs[i] = make_float4(d * v.x, d * v.y, d * v.z, d * v.w);
}

// ================= CSR gathers (prescaled source, edge-split lanes) =================
// 8 lanes per node; each handles every 8th edge; 3-level shfl_xor reduce.
__global__ __launch_bounds__(256) void k_gather3(const int* __restrict__ rp, const int* __restrict__ cs,
                          const float4* __restrict__ xs, const float* __restrict__ dinv,
                          const float* __restrict__ sub, float* __restrict__ dst,
                          float4* __restrict__ xs_out, int N, float scale){
  int tid = blockIdx.x * 256 + threadIdx.x;
  int n = tid >> 3, q = tid & 7;
  if (n >= N) return;
  int e0 = rp[n], e1 = rp[n + 1];
  float a0 = 0.f, a1 = 0.f, a2 = 0.f;
  for (int e = e0 + q; e < e1; e += 8){
    float4 v = xs[cs[e]];
    a0 += v.x; a1 += v.y; a2 += v.z;
  }
  a0 += __shfl_xor(a0, 1); a1 += __shfl_xor(a1, 1); a2 += __shfl_xor(a2, 1);
  a0 += __shfl_xor(a0, 2); a1 += __shfl_xor(a1, 2); a2 += __shfl_xor(a2, 2);
  a0 += __shfl_xor(a0, 4); a1 += __shfl_xor(a1, 4); a2 += __shfl_xor(a2, 4);
  if (q == 0){
    float dn = dinv[n];
    float m = -scale * dn;
    float r0 = m * a0, r1 = m * a1, r2 = m * a2;
    if (sub){ r0 -= sub[n * 3 + 0]; r1 -= sub[n * 3 + 1]; r2 -= sub[n * 3 + 2]; }
    dst[n * 3 + 0] = r0; dst[n * 3 + 1] = r1; dst[n * 3 + 2] = r2;
    if (xs_out) xs_out[n] = make_float4(dn * r0, dn * r1, dn * r2, 0.f);
  }
}

// G = 4L lanes per node: f4 = q%L, edge-split es = q/L (0..3); 2-level shfl_xor reduce.
template<int F>
__global__ __launch_bounds__(256) void k_gatherT(const int* __restrict__ rp, const int* __restrict__ cs,
                          const float4* __restrict__ xs, const float* __restrict__ dinv,
                          const float* __restrict__ sub, float* __restrict__ dst,
                          float4* __restrict__ xs_out, int N, float scale){
  constexpr int L = F / 4;
  constexpr int G = 4 * L;
  int tid = blockIdx.x * 256 + threadIdx.x;
  int n = tid / G, q = tid % G;
  if (n >= N) return;
  int f4 = q % L, es = q / L;
  int e0 = rp[n], e1 = rp[n + 1];
  float4 acc = make_float4(0.f, 0.f, 0.f, 0.f);
  for (int e = e0 + es; e < e1; e += 4){
    float4 v = xs[(long)cs[e] * L + f4];
    acc.x += v.x; acc.y += v.y; acc.z += v.z; acc.w += v.w;
  }
  acc.x += __shfl_xor(acc.x, L);     acc.y += __shfl_xor(acc.y, L);
  acc.z += __shfl_xor(acc.z, L);     acc.w += __shfl_xor(acc.w, L);
  acc.x += __shfl_xor(acc.x, 2 * L); acc.y += __shfl_xor(acc.y, 2 * L);
  acc.z += __shfl_xor(acc.z, 2 * L); acc.w += __shfl_xor(acc.w, 2 * L);
  if (es == 0){
    float dn = dinv[n];
    float m = -scale * dn;
    float4 r = make_float4(m * acc.x, m * acc.y, m * acc.z, m * acc.w);
    if (sub){
      float4 sv = ((const float4*)sub)[(long)n * L + f4];
      r.x -= sv.x; r.y -= sv.y; r.z -= sv.z; r.w -= sv.w;
    }
    ((float4*)dst)[(long)n * L + f4] = r;
    if (xs_out) xs_out[(long)n * L + f4] = make_float4(dn * r.x, dn * r.y, dn * r.z, dn * r.w);
  }
}

template<int F>
__global__ __launch_bounds__(256) void k_gatherP(const int* __restrict__ rp, const int* __restrict__ cs,
                          const float* __restrict__ wv, const float* __restrict__ h,
                          float* __restrict__ dst, int N){
  constexpr int L = F / 4;
  int tid = blockIdx.x * 256 + threadIdx.x;
  int n = tid / L, q = tid % L;
  if (n >= N) return;
  const float4* h4 = (const float4*)h;
  int e0 = rp[n], e1 = rp[n + 1];
  float4 acc = make_float4(0.f, 0.f, 0.f, 0.f);
  for (int e = e0; e < e1; e++){
    int c = cs[e];
    float w = wv[e];
    float4 v = h4[(long)c * L + q];
    acc.x = fmaf(w, v.x, acc.x); acc.y = fmaf(w, v.y, acc.y);
    acc.z = fmaf(w, v.z, acc.z); acc.w = fmaf(w, v.w, acc.w);
  }
  ((float4*)dst)[(long)n * L + q] = acc;
}

// ================= dense cheb contraction, LDS-tiled =================
template<int F, int FO, int R, bool RELU>
__global__ __launch_bounds__(256) void k_cheb_tile(const float* __restrict__ x, const float* __restrict__ T, int N,
                           const float* __restrict__ W, const float* __restrict__ b,
                           float* __restrict__ out){
  constexpr int OQ4  = FO / 4;
  constexpr int NSUB = 256 / OQ4;
  constexpr int NT   = NSUB * R;
  constexpr int F6   = KCH * F;
  int n0 = blockIdx.x * NT;
  int o4   = threadIdx.x % OQ4;
  int nsub = threadIdx.x / OQ4;
  const float4* W4 = (const float4*)W;       // [F6][OQ4]
  float4 acc[R];
  float4 bb = ((const float4*)b)[o4];
#pragma unroll
  for (int r = 0; r < R; r++) acc[r] = bb;

  if constexpr (F == 3){
    constexpr int PITCH = F6 + 2;
    __shared__ float X[NT * PITCH];
    for (int i = threadIdx.x; i < NT * F6; i += 256){
      int k = i / (NT * 3);
      int idx = i - k * (NT * 3);
      const float* src = (k == 0) ? x : (T + (size_t)(k - 1) * N * 3);
      int node = idx / 3, j = idx - node * 3;
      float v = (n0 + node < N) ? src[(long)n0 * 3 + idx] : 0.f;
      X[node * PITCH + k * 3 + j] = v;
    }
    __syncthreads();
#pragma unroll
    for (int f = 0; f < F6; f++){
      float4 w = W4[(long)f * OQ4 + o4];
#pragma unroll
      for (int r = 0; r < R; r++){
        float v = X[(nsub * R + r) * PITCH + f];
        acc[r].x = fmaf(v, w.x, acc[r].x); acc[r].y = fmaf(v, w.y, acc[r].y);
        acc[r].z = fmaf(v, w.z, acc[r].z); acc[r].w = fmaf(v, w.w, acc[r].w);
      }
    }
  } else {
    constexpr int L  = F / 4;
    constexpr int P4 = F6 / 4 + 1;
    __shared__ float4 X[NT * P4];
    for (int i = threadIdx.x; i < NT * KCH * L; i += 256){
      int k = i / (NT * L);
      int idx = i - k * (NT * L);
      int node = idx / L, q = idx - node * L;
      const float4* src4 = (const float4*)((k == 0) ? x : (T + (size_t)(k - 1) * N * F));
      float4 v = make_float4(0.f, 0.f, 0.f, 0.f);
      if (n0 + node < N) v = src4[(long)n0 * L + idx];
      X[node * P4 + k * L + q] = v;
    }
    __syncthreads();
#pragma unroll 4
    for (int f4 = 0; f4 < F6 / 4; f4++){
      float4 w0 = W4[(long)(4 * f4 + 0) * OQ4 + o4];
      float4 w1 = W4[(long)(4 * f4 + 1) * OQ4 + o4];
      float4 w2 = W4[(long)(4 * f4 + 2) * OQ4 + o4];
      float4 w3 = W4[(long)(4 * f4 + 3) * OQ4 + o4];
#pragma unroll
      for (int r = 0; r < R; r++){
        float4 hv = X[(nsub * R + r) * P4 + f4];
        acc[r].x = fmaf(hv.x, w0.x, acc[r].x); acc[r].y = fmaf(hv.x, w0.y, acc[r].y);
        acc[r].z = fmaf(hv.x, w0.z, acc[r].z); acc[r].w = fmaf(hv.x, w0.w, acc[r].w);
        acc[r].x = fmaf(hv.y, w1.x, acc[r].x); acc[r].y = fmaf(hv.y, w1.y, acc[r].y);
        acc[r].z = fmaf(hv.y, w1.z, acc[r].z); acc[r].w = fmaf(hv.y, w1.w, acc[r].w);
        acc[r].x = fmaf(hv.z, w2.x, acc[r].x); acc[r].y = fmaf(hv.z, w2.y, acc[r].y);
        acc[r].z = fmaf(hv.z, w2.z, acc[r].z); acc[r].w = fmaf(hv.z, w2.w, acc[r].w);
        acc[r].x = fmaf(hv.w, w3.x, acc[r].x); acc[r].y = fmaf(hv.w, w3.y, acc[r].y);
        acc[r].z = fmaf(hv.w, w3.z, acc[r].z); acc[r].w = fmaf(hv.w, w3.w, acc[r].w);
      }
    }
  }

#pragma unroll
  for (int r = 0; r < R; r++){
    int n = n0 + nsub * R + r;
    if (n < N){
      float4 o = acc[r];
      if (RELU){
        o.x = fmaxf(o.x, 0.f); o.y = fmaxf(o.y, 0.f);
        o.z = fmaxf(o.z, 0.f); o.w = fmaxf(o.w, 0.f);
      }
      ((float4*)out)[(long)n * OQ4 + o4] = o;
    }
  }
}

// ================= final hidden GEMM + global max + classifier =================
__device__ __forceinline__ unsigned fmap(float x){
  unsigned u = __float_as_uint(x);
  return (u & 0x80000000u) ? ~u : (u | 0x80000000u);
}
__device__ __forceinline__ float funmap(unsigned u){
  return (u & 0x80000000u) ? __uint_as_float(u ^ 0x80000000u) : __uint_as_float(~u);
}

#define NT 32
__global__ __launch_bounds__(256) void k_hidden_max(const float* __restrict__ h2, const float* __restrict__ Wh,
                             const float* __restrict__ bh, unsigned* __restrict__ maxed, int N){
  __shared__ float4 sh4[NT * 32];        // 16 KB
  int n0 = blockIdx.y * NT;
  for (int i = threadIdx.x; i < NT * 32; i += 256){
    int n = i >> 5;
    float4 v = make_float4(0.f, 0.f, 0.f, 0.f);
    if (n0 + n < N) v = ((const float4*)h2)[(long)(n0 + n) * 32 + (i & 31)];
    sh4[i] = v;
  }
  __syncthreads();
  int o4l  = threadIdx.x & 31;
  int nsub = threadIdx.x >> 5;
  int o4   = blockIdx.x * 32 + o4l;
  const float4* Wh4 = (const float4*)Wh;
  float4 acc[4];
#pragma unroll
  for (int j = 0; j < 4; j++) acc[j] = make_float4(0.f, 0.f, 0.f, 0.f);
#pragma unroll 2
  for (int f4 = 0; f4 < 32; f4++){
    float4 w0 = Wh4[(long)(4 * f4 + 0) * 256 + o4];
    float4 w1 = Wh4[(long)(4 * f4 + 1) * 256 + o4];
    float4 w2 = Wh4[(long)(4 * f4 + 2) * 256 + o4];
    float4 w3 = Wh4[(long)(4 * f4 + 3) * 256 + o4];
#pragma unroll
    for (int j = 0; j < 4; j++){
      float4 hv = sh4[(nsub * 4 + j) * 32 + f4];
      acc[j].x = fmaf(hv.x, w0.x, acc[j].x); acc[j].y = fmaf(hv.x, w0.y, acc[j].y);
      acc[j].z = fmaf(hv.x, w0.z, acc[j].z); acc[j].w = fmaf(hv.x, w0.w, acc[j].w);
      acc[j].x = fmaf(hv.y, w1.x, acc[j].x); acc[j].y = fmaf(hv.y, w1.y, acc[j].y);
      acc[j].z = fmaf(hv.y, w1.z, acc[j].z); acc[j].w = fmaf(hv.y, w1.w, acc[j].w);
      acc[j].x = fmaf(hv.z, w2.x, acc[j].x); acc[j].y = fmaf(hv.z, w2.y, acc[j].y);
      acc[j].z = fmaf(hv.z, w2.z, acc[j].z); acc[j].w = fmaf(hv.z, w2.w, acc[j].w);
      acc[j].x = fmaf(hv.w, w3.x, acc[j].x); acc[j].y = fmaf(hv.w, w3.y, acc[j].y);
      acc[j].z = fmaf(hv.w, w3.z, acc[j].z); acc[j].w = fmaf(hv.w, w3.w, acc[j].w);
    }
  }
  float4 m = make_float4(-INFINITY, -INFINITY, -INFINITY, -INFINITY);
#pragma unroll
  for (int j = 0; j < 4; j++){
    if (n0 + nsub * 4 + j < N){
      m.x = fmaxf(m.x, acc[j].x); m.y = fmaxf(m.y, acc[j].y);
      m.z = fmaxf(m.z, acc[j].z); m.w = fmaxf(m.w, acc[j].w);
    }
  }
  __syncthreads();
  sh4[nsub * 32 + o4l] = m;
  __syncthreads();
  if (nsub == 0){
#pragma unroll
    for (int s = 1; s < 8; s++){
      float4 o = sh4[s * 32 + o4l];
      m.x = fmaxf(m.x, o.x); m.y = fmaxf(m.y, o.y);
      m.z = fmaxf(m.z, o.z); m.w = fmaxf(m.w, o.w);
    }
    float4 b4 = ((const float4*)bh)[o4];
    atomicMax(&maxed[4 * o4 + 0], fmap(m.x + b4.x));
    atomicMax(&maxed[4 * o4 + 1], fmap(m.y + b4.y));
    atomicMax(&maxed[4 * o4 + 2], fmap(m.z + b4.z));
    atomicMax(&maxed[4 * o4 + 3], fmap(m.w + b4.w));
  }
}

__global__ __launch_bounds__(64) void k_final(const unsigned* __restrict__ maxed, const float* __restrict__ Wl,
                        const float* __restrict__ bl, float* __restrict__ out){
  int c = blockIdx.x;
  int l = threadIdx.x;
  float acc = 0.f;
  for (int o = l; o < 1024; o += 64)
    acc = fmaf(funmap(maxed[o]), Wl[o * NCLS + c], acc);
  for (int off = 32; off > 0; off >>= 1)
    acc += __shfl_down(acc, off);
  if (l == 0) out[c] = acc + bl[c];
}

// ================= drivers =================
static void run_scan(int* gh, int M, int* bsum, int* rp, int N, int E, hipStream_t s){
  int nb = cdiv(M, SCB);
  k_scanA<<<nb, 256, 0, s>>>(gh, M, bsum);
  k_scanC<<<nb, 256, 0, s>>>(gh, M, bsum, rp, N, E);
}

template<int F, int FO, int R, bool RELU>
static void run_cheb(const int* row, const int* col, int E, int N,
                     const float* x, const float* W, const float* b, float* out,
                     unsigned* ebuf, int* cs, float* T, float4* xsA, float4* xsB,
                     int* rp, float* dinv, int* gh, int* bsum, hipStream_t s){
  int nbkt = cdiv(N, RPB);
  int chunk = cdiv(E, NBLK);
  k_phist<<<NBLK, 256, 0, s>>>(row, E, chunk, gh, nbkt);
  run_scan(gh, nbkt * NBLK, bsum, rp, N, E, s);
  k_pscatter<false><<<NBLK, 256, 0, s>>>(row, col, E, chunk, gh, ebuf, nbkt);
  k_bfinal<false><<<nbkt, 512, 0, s>>>(ebuf, gh, nbkt, N, E, nullptr, nullptr, rp, dinv, cs, nullptr);

  // prescale first source
  if constexpr (F == 3)
    k_prescale3<<<cdiv(N, 256), 256, 0, s>>>(x, dinv, xsA, N);
  else
    k_prescaleF<F><<<cdiv((long)N * (F / 4), 256), 256, 0, s>>>(x, dinv, xsA, N);

  const float* sub = nullptr; float scale = 1.f;
  float4* xin = xsA; float4* xout = xsB;
  const float* srcRaw = x;
  for (int k = 1; k < KCH; k++){
    float* Tk = T + (size_t)(k - 1) * N * F;
    float4* xo = (k == KCH - 1) ? nullptr : xout;
    if constexpr (F == 3)
      k_gather3<<<cdiv((long)N * 8, 256), 256, 0, s>>>(rp, cs, xin, dinv, sub, Tk, xo, N, scale);
    else
      k_gatherT<F><<<cdiv((long)N * F, 256), 256, 0, s>>>(rp, cs, xin, dinv, sub, Tk, xo, N, scale);
    sub = srcRaw; srcRaw = Tk; scale = 2.f;
    float4* t = xin; xin = xout; xout = t;
  }
  constexpr int NTC = (256 / (FO / 4)) * R;
  k_cheb_tile<F, FO, R, RELU><<<cdiv(N, NTC), 256, 0, s>>>(x, T, N, W, b, out);
}

template<int F>
static void run_pool(const int* row, const int* col, const float* val, int E, int Nout,
                     const float* h, float* out, unsigned* ebuf, int* cs, float* wv,
                     int* rp, int* gh, int* bsum, hipStream_t s){
  int nbkt = cdiv(Nout, RPB);
  int chunk = cdiv(E, NBLK);
  k_phist<<<NBLK, 256, 0, s>>>(row, E, chunk, gh, nbkt);
  run_scan(gh, nbkt * NBLK, bsum, rp, Nout, E, s);
  k_pscatter<true><<<NBLK, 256, 0, s>>>(row, col, E, chunk, gh, ebuf, nbkt);
  k_bfinal<true><<<nbkt, 512, 0, s>>>(ebuf, gh, nbkt, Nout, E, col, val, rp, nullptr, cs, wv);
  k_gatherP<F><<<cdiv((long)Nout * (F / 4), 256), 256, 0, s>>>(rp, cs, wv, h, out, Nout);
}

extern "C" void kernel_launch(void* const* d_in, const int* in_sizes, int n_in,
                              void* d_out, int out_size, void* d_ws, size_t ws_size,
                              hipStream_t stream){
  const float* pos = (const float*)d_in[0];
  const int*   ei0 = (const int*)d_in[1];
  const int*   ei1 = (const int*)d_in[2];
  const int*   ei2 = (const int*)d_in[3];
  const int*   p0r = (const int*)d_in[4];
  const int*   p0c = (const int*)d_in[5];
  const float* p0v = (const float*)d_in[6];
  const int*   p1r = (const int*)d_in[7];
  const int*   p1c = (const int*)d_in[8];
  const float* p1v = (const float*)d_in[9];
  const float* W0  = (const float*)d_in[10]; const float* b0 = (const float*)d_in[11];
  const float* W1  = (const float*)d_in[12]; const float* b1 = (const float*)d_in[13];
  const float* W2  = (const float*)d_in[14]; const float* b2 = (const float*)d_in[15];
  const float* Wh  = (const float*)d_in[16]; const float* bh = (const float*)d_in[17];
  const float* Wl  = (const float*)d_in[18]; const float* bl = (const float*)d_in[19];
  float* out = (float*)d_out;

  // workspace layout (float-sized units)
  float* SCR = (float*)d_ws;                 // 4.8M floats, per-stage overlays
  float* hA  = SCR + 4800000;                // 3.2M  (N0*32 / N2*128; L1 xs ping-pong)
  float* hB  = hA + 3200000;                 // 1.6M  (N1*64; L0 xs ping-pong)
  float* hC  = hB + 1600000;                 // 0.8M  (N1*32 / N2*64)
  int* rp     = (int*)(hC + 800000);         // 100001
  float* dinv = (float*)(rp + 100001);       // 100000
  int* gh     = (int*)(dinv + 100000);       // 47040 (196*240 max)
  int* bsum   = gh + 47040;                  // 16
  unsigned* maxed = (unsigned*)(bsum + 16);  // 1024

  // layer 0: cheb(pos) -> hA [N0,32], relu.
  run_cheb<3, 32, 2, true>(ei0, ei0 + E0G, E0G, N0G, pos, W0, b0, hA,
                        (unsigned*)SCR, (int*)(SCR + 1600000), SCR + 3200000,
                        (float4*)hB, (float4*)(hB + 400000),
                        rp, dinv, gh, bsum, stream);

  // pool 0: hA -> hC [N1,32].
  run_pool<32>(p0r, p0c, p0v, N0G, N1G, hA, hC,
               (unsigned*)SCR, (int*)(SCR + 100000), SCR + 200000,
               rp, gh, bsum, stream);

  // layer 1: cheb(hC) -> hB [N1,64], relu.
  run_cheb<32, 64, 2, true>(ei1, ei1 + E1G, E1G, N1G, hC, W1, b1, hB,
                         (unsigned*)SCR, (int*)(SCR + 400000), SCR + 800000,
                         (float4*)hA, (float4*)(hA + 800000),
                         rp, dinv, gh, bsum, stream);

  // pool 1: hB -> hC [N2,64].
  run_pool<64>(p1r, p1c, p1v, N1G, N2G, hB, hC,
               (unsigned*)SCR, (int*)(SCR + 25000), SCR + 50000,
               rp, gh, bsum, stream);

  // layer 2: cheb(hC) -> hA [N2,128], no relu.
  run_cheb<64, 128, 2, false>(ei2, ei2 + E2G, E2G, N2G, hC, W2, b2, hA,
                           (unsigned*)SCR, (int*)(SCR + 100000), SCR + 200000,
                           (float4*)(SCR + 2200000), (float4*)(SCR + 2600000),
                           rp, dinv, gh, bsum, stream);

  // hidden GEMM + global max over nodes
  hipMemsetAsync(maxed, 0, 1024 * sizeof(unsigned), stream);
  dim3 g(8, cdiv(N2G, NT));
  k_hidden_max<<<g, 256, 0, stream>>>(hA, Wh, bh, maxed, N2G);

  // classifier
  k_final<<<NCLS, 64, 0, stream>>>(maxed, Wl, bl, out);
}

// Round 13
// 450.311 us; speedup vs baseline: 1.3016x; 1.0076x over previous
//
#include <hip/hip_runtime.h>
#include <cstdint>
#include <cmath>

#define N0G 100000
#define N1G 25000
#define N2G 6250
#define E0G 1600000
#define E1G 400000
#define E2G 100000
#define KCH 6
#define NCLS 40
#define RPB 512            // rows per bucket (9 bits local row)
#define NBLK 240           // binning blocks
#define PAYB 17            // payload bits (col or edge idx < 131072)
#define SCT 16             // scan elems per thread
#define SCB (256 * SCT)    // scan elems per block

static inline int cdiv(long a, long b){ return (int)((a + b - 1) / b); }

// ================= deterministic bucket CSR build =================
__global__ __launch_bounds__(256) void k_phist(const int* __restrict__ row, int E, int chunk,
                                               int* __restrict__ gh, int nbkt){
  __shared__ int h[256];
  for (int i = threadIdx.x; i < nbkt; i += 256) h[i] = 0;
  __syncthreads();
  int e0 = blockIdx.x * chunk, e1 = min(E, e0 + chunk);
  for (int e = e0 + threadIdx.x; e < e1; e += 256)
    atomicAdd(&h[row[e] >> 9], 1);
  __syncthreads();
  for (int i = threadIdx.x; i < nbkt; i += 256)
    gh[i * NBLK + blockIdx.x] = h[i];
}

__global__ __launch_bounds__(256) void k_scanA(const int* __restrict__ gh, int M, int* __restrict__ bsum){
  __shared__ int sh[256];
  int base = blockIdx.x * SCB + threadIdx.x * SCT;
  int s = 0;
#pragma unroll
  for (int j = 0; j < SCT; j++){ int i = base + j; if (i < M) s += gh[i]; }
  sh[threadIdx.x] = s; __syncthreads();
  for (int o = 128; o > 0; o >>= 1){
    if (threadIdx.x < o) sh[threadIdx.x] += sh[threadIdx.x + o];
    __syncthreads();
  }
  if (threadIdx.x == 0) bsum[blockIdx.x] = sh[0];
}

__global__ __launch_bounds__(256) void k_scanC(int* __restrict__ gh, int M, const int* __restrict__ bsum,
                                               int* __restrict__ rp, int N, int E, int nb){
  __shared__ int sh[256];
  __shared__ int blockoff;
  if (threadIdx.x == 0){
    int off = 0;
    if (nb > 1) for (int j = 0; j < (int)blockIdx.x; j++) off += bsum[j];
    blockoff = off;
  }
  int base = blockIdx.x * SCB + threadIdx.x * SCT;
  int v[SCT]; int s = 0;
#pragma unroll
  for (int j = 0; j < SCT; j++){ int i = base + j; v[j] = (i < M) ? gh[i] : 0; s += v[j]; }
  sh[threadIdx.x] = s;
  __syncthreads();
  for (int o = 1; o < 256; o <<= 1){
    int t = (threadIdx.x >= o) ? sh[threadIdx.x - o] : 0;
    __syncthreads();
    sh[threadIdx.x] += t;
    __syncthreads();
  }
  int excl = blockoff + sh[threadIdx.x] - s;
#pragma unroll
  for (int j = 0; j < SCT; j++){
    int i = base + j;
    if (i < M){ gh[i] = excl; excl += v[j]; }
  }
  if (blockIdx.x == 0 && threadIdx.x == 0) rp[N] = E;
}

template<bool POOL>
__global__ __launch_bounds__(256) void k_pscatter(const int* __restrict__ row, const int* __restrict__ col,
                                                  int E, int chunk, const int* __restrict__ gh,
                                                  unsigned* __restrict__ ebuf, int nbkt){
  __shared__ int cur[256];
  for (int i = threadIdx.x; i < nbkt; i += 256) cur[i] = gh[i * NBLK + blockIdx.x];
  __syncthreads();
  int e0 = blockIdx.x * chunk, e1 = min(E, e0 + chunk);
  for (int e = e0 + threadIdx.x; e < e1; e += 256){
    int r = row[e];
    int dst = atomicAdd(&cur[r >> 9], 1);
    unsigned pay = POOL ? (unsigned)e : (unsigned)col[e];
    ebuf[dst] = ((unsigned)(r & 511) << PAYB) | pay;
  }
}

// F>0 (graph): also computes dinv and writes prescaled xs row = dinv[n]*x[n,:]
template<bool POOL, int F>
__global__ __launch_bounds__(512) void k_bfinal(const unsigned* __restrict__ ebuf,
                                                const int* __restrict__ gh, int nbkt, int N, int E,
                                                const int* __restrict__ pcol, const float* __restrict__ pval,
                                                int* __restrict__ rp, float* __restrict__ dinv,
                                                int* __restrict__ cs, float* __restrict__ wv,
                                                const float* __restrict__ x, float4* __restrict__ xs){
  __shared__ int h[512];
  __shared__ int cur[512];
  int b = blockIdx.x;
  int e0 = gh[b * NBLK];
  int e1 = (b + 1 < nbkt) ? gh[(b + 1) * NBLK] : E;
  int r0 = b * RPB;
  int t = threadIdx.x;
  h[t] = 0;
  __syncthreads();
  for (int e = e0 + t; e < e1; e += 512)
    atomicAdd(&h[ebuf[e] >> PAYB], 1);
  __syncthreads();
  int cnt = h[t];
  __syncthreads();
  for (int o = 1; o < 512; o <<= 1){
    int tmp = (t >= o) ? h[t - o] : 0;
    __syncthreads();
    h[t] += tmp;
    __syncthreads();
  }
  int excl = h[t] - cnt;
  cur[t] = excl;
  int n = r0 + t;
  if (n < N){
    rp[n] = e0 + excl;
    if constexpr (!POOL){
      float d = cnt > 0 ? rsqrtf((float)cnt) : 0.f;
      dinv[n] = d;
      if constexpr (F == 3){
        xs[n] = make_float4(d * x[n * 3 + 0], d * x[n * 3 + 1], d * x[n * 3 + 2], 0.f);
      } else if constexpr (F > 0){
        constexpr int L = F / 4;
        const float4* x4 = (const float4*)x;
#pragma unroll
        for (int q = 0; q < L; q++){
          float4 v = x4[(long)n * L + q];
          xs[(long)n * L + q] = make_float4(d * v.x, d * v.y, d * v.z, d * v.w);
        }
      }
    }
  }
  __syncthreads();
  for (int e = e0 + t; e < e1; e += 512){
    unsigned u = ebuf[e];
    int p = atomicAdd(&cur[u >> PAYB], 1);
    int dst = e0 + p;
    if (POOL){
      int ei = (int)(u & ((1u << PAYB) - 1));
      cs[dst] = pcol[ei]; wv[dst] = pval[ei];
    } else {
      cs[dst] = (int)(u & ((1u << PAYB) - 1));
    }
  }
}

// ================= CSR gathers (prescaled source, edge-split lanes) =================
__global__ __launch_bounds__(256) void k_gather3(const int* __restrict__ rp, const int* __restrict__ cs,
                          const float4* __restrict__ xs, const float* __restrict__ dinv,
                          const float* __restrict__ sub, float* __restrict__ dst,
                          float4* __restrict__ xs_out, int N, float scale){
  int tid = blockIdx.x * 256 + threadIdx.x;
  int n = tid >> 3, q = tid & 7;
  if (n >= N) return;
  int e0 = rp[n], e1 = rp[n + 1];
  float a0 = 0.f, a1 = 0.f, a2 = 0.f;
  for (int e = e0 + q; e < e1; e += 8){
    float4 v = xs[cs[e]];
    a0 += v.x; a1 += v.y; a2 += v.z;
  }
  a0 += __shfl_xor(a0, 1); a1 += __shfl_xor(a1, 1); a2 += __shfl_xor(a2, 1);
  a0 += __shfl_xor(a0, 2); a1 += __shfl_xor(a1, 2); a2 += __shfl_xor(a2, 2);
  a0 += __shfl_xor(a0, 4); a1 += __shfl_xor(a1, 4); a2 += __shfl_xor(a2, 4);
  if (q == 0){
    float dn = dinv[n];
    float m = -scale * dn;
    float r0 = m * a0, r1 = m * a1, r2 = m * a2;
    if (sub){ r0 -= sub[n * 3 + 0]; r1 -= sub[n * 3 + 1]; r2 -= sub[n * 3 + 2]; }
    dst[n * 3 + 0] = r0; dst[n * 3 + 1] = r1; dst[n * 3 + 2] = r2;
    if (xs_out) xs_out[n] = make_float4(dn * r0, dn * r1, dn * r2, 0.f);
  }
}

template<int F>
__global__ __launch_bounds__(256) void k_gatherT(const int* __restrict__ rp, const int* __restrict__ cs,
                          const float4* __restrict__ xs, const float* __restrict__ dinv,
                          const float* __restrict__ sub, float* __restrict__ dst,
                          float4* __restrict__ xs_out, int N, float scale){
  constexpr int L = F / 4;
  constexpr int G = 4 * L;
  int tid = blockIdx.x * 256 + threadIdx.x;
  int n = tid / G, q = tid % G;
  if (n >= N) return;
  int f4 = q % L, es = q / L;
  int e0 = rp[n], e1 = rp[n + 1];
  float4 acc = make_float4(0.f, 0.f, 0.f, 0.f);
  for (int e = e0 + es; e < e1; e += 4){
    float4 v = xs[(long)cs[e] * L + f4];
    acc.x += v.x; acc.y += v.y; acc.z += v.z; acc.w += v.w;
  }
  acc.x += __shfl_xor(acc.x, L);     acc.y += __shfl_xor(acc.y, L);
  acc.z += __shfl_xor(acc.z, L);     acc.w += __shfl_xor(acc.w, L);
  acc.x += __shfl_xor(acc.x, 2 * L); acc.y += __shfl_xor(acc.y, 2 * L);
  acc.z += __shfl_xor(acc.z, 2 * L); acc.w += __shfl_xor(acc.w, 2 * L);
  if (es == 0){
    float dn = dinv[n];
    float m = -scale * dn;
    float4 r = make_float4(m * acc.x, m * acc.y, m * acc.z, m * acc.w);
    if (sub){
      float4 sv = ((const float4*)sub)[(long)n * L + f4];
      r.x -= sv.x; r.y -= sv.y; r.z -= sv.z; r.w -= sv.w;
    }
    ((float4*)dst)[(long)n * L + f4] = r;
    if (xs_out) xs_out[(long)n * L + f4] = make_float4(dn * r.x, dn * r.y, dn * r.z, dn * r.w);
  }
}

template<int F>
__global__ __launch_bounds__(256) void k_gatherP(const int* __restrict__ rp, const int* __restrict__ cs,
                          const float* __restrict__ wv, const float* __restrict__ h,
                          float* __restrict__ dst, int N){
  constexpr int L = F / 4;
  int tid = blockIdx.x * 256 + threadIdx.x;
  int n = tid / L, q = tid % L;
  if (n >= N) return;
  const float4* h4 = (const float4*)h;
  int e0 = rp[n], e1 = rp[n + 1];
  float4 acc = make_float4(0.f, 0.f, 0.f, 0.f);
  for (int e = e0; e < e1; e++){
    int c = cs[e];
    float w = wv[e];
    float4 v = h4[(long)c * L + q];
    acc.x = fmaf(w, v.x, acc.x); acc.y = fmaf(w, v.y, acc.y);
    acc.z = fmaf(w, v.z, acc.z); acc.w = fmaf(w, v.w, acc.w);
  }
  ((float4*)dst)[(long)n * L + q] = acc;
}

// ================= dense cheb contraction, LDS-tiled =================
template<int F, int FO, int R, bool RELU>
__global__ __launch_bounds__(256) void k_cheb_tile(const float* __restrict__ x, const float* __restrict__ T, int N,
                           const float* __restrict__ W, const float* __restrict__ b,
                           float* __restrict__ out){
  constexpr int OQ4  = FO / 4;
  constexpr int NSUB = 256 / OQ4;
  constexpr int NT   = NSUB * R;
  constexpr int F6   = KCH * F;
  int n0 = blockIdx.x * NT;
  int o4   = threadIdx.x % OQ4;
  int nsub = threadIdx.x / OQ4;
  const float4* W4 = (const float4*)W;       // [F6][OQ4]
  float4 acc[R];
  float4 bb = ((const float4*)b)[o4];
#pragma unroll
  for (int r = 0; r < R; r++) acc[r] = bb;

  if constexpr (F == 3){
    constexpr int PITCH = F6 + 2;
    __shared__ float X[NT * PITCH];
    for (int i = threadIdx.x; i < NT * F6; i += 256){
      int k = i / (NT * 3);
      int idx = i - k * (NT * 3);
      const float* src = (k == 0) ? x : (T + (size_t)(k - 1) * N * 3);
      int node = idx / 3, j = idx - node * 3;
      float v = (n0 + node < N) ? src[(long)n0 * 3 + idx] : 0.f;
      X[node * PITCH + k * 3 + j] = v;
    }
    __syncthreads();
#pragma unroll
    for (int f = 0; f < F6; f++){
      float4 w = W4[(long)f * OQ4 + o4];
#pragma unroll
      for (int r = 0; r < R; r++){
        float v = X[(nsub * R + r) * PITCH + f];
        acc[r].x = fmaf(v, w.x, acc[r].x); acc[r].y = fmaf(v, w.y, acc[r].y);
        acc[r].z = fmaf(v, w.z, acc[r].z); acc[r].w = fmaf(v, w.w, acc[r].w);
      }
    }
  } else {
    constexpr int L  = F / 4;
    constexpr int P4 = F6 / 4 + 1;
    __shared__ float4 X[NT * P4];
    for (int i = threadIdx.x; i < NT * KCH * L; i += 256){
      int k = i / (NT * L);
      int idx = i - k * (NT * L);
      int node = idx / L, q = idx - node * L;
      const float4* src4 = (const float4*)((k == 0) ? x : (T + (size_t)(k - 1) * N * F));
      float4 v = make_float4(0.f, 0.f, 0.f, 0.f);
      if (n0 + node < N) v = src4[(long)n0 * L + idx];
      X[node * P4 + k * L + q] = v;
    }
    __syncthreads();
#pragma unroll 4
    for (int f4 = 0; f4 < F6 / 4; f4++){
      float4 w0 = W4[(long)(4 * f4 + 0) * OQ4 + o4];
      float4 w1 = W4[(long)(4 * f4 + 1) * OQ4 + o4];
      float4 w2 = W4[(long)(4 * f4 + 2) * OQ4 + o4];
      float4 w3 = W4[(long)(4 * f4 + 3) * OQ4 + o4];
#pragma unroll
      for (int r = 0; r < R; r++){
        float4 hv = X[(nsub * R + r) * P4 + f4];
        acc[r].x = fmaf(hv.x, w0.x, acc[r].x); acc[r].y = fmaf(hv.x, w0.y, acc[r].y);
        acc[r].z = fmaf(hv.x, w0.z, acc[r].z); acc[r].w = fmaf(hv.x, w0.w, acc[r].w);
        acc[r].x = fmaf(hv.y, w1.x, acc[r].x); acc[r].y = fmaf(hv.y, w1.y, acc[r].y);
        acc[r].z = fmaf(hv.y, w1.z, acc[r].z); acc[r].w = fmaf(hv.y, w1.w, acc[r].w);
        acc[r].x = fmaf(hv.z, w2.x, acc[r].x); acc[r].y = fmaf(hv.z, w2.y, acc[r].y);
        acc[r].z = fmaf(hv.z, w2.z, acc[r].z); acc[r].w = fmaf(hv.z, w2.w, acc[r].w);
        acc[r].x = fmaf(hv.w, w3.x, acc[r].x); acc[r].y = fmaf(hv.w, w3.y, acc[r].y);
        acc[r].z = fmaf(hv.w, w3.z, acc[r].z); acc[r].w = fmaf(hv.w, w3.w, acc[r].w);
      }
    }
  }

#pragma unroll
  for (int r = 0; r < R; r++){
    int n = n0 + nsub * R + r;
    if (n < N){
      float4 o = acc[r];
      if (RELU){
        o.x = fmaxf(o.x, 0.f); o.y = fmaxf(o.y, 0.f);
        o.z = fmaxf(o.z, 0.f); o.w = fmaxf(o.w, 0.f);
      }
      ((float4*)out)[(long)n * OQ4 + o4] = o;
    }
  }
}

// ================= final hidden GEMM + global max + classifier =================
__device__ __forceinline__ unsigned fmap(float x){
  unsigned u = __float_as_uint(x);
  return (u & 0x80000000u) ? ~u : (u | 0x80000000u);
}
__device__ __forceinline__ float funmap(unsigned u){
  return (u & 0x80000000u) ? __uint_as_float(u ^ 0x80000000u) : __uint_as_float(~u);
}

// grid (8 o-tiles, 64). Block: Wh o-slice (128f x 32 float4 = 64KB) + h tile (32n x 32f4 = 16KB)
// both in LDS; inner loop pure LDS+FMA. Thread = 1 float4 output x 4 nodes.
#define NT 32
__global__ __launch_bounds__(256) void k_hidden_max(const float* __restrict__ h2, const float* __restrict__ Wh,
                             const float* __restrict__ bh, unsigned* __restrict__ maxed, int N){
  __shared__ float4 sW[128 * 32];        // [f][o4l] 64 KB
  __shared__ float4 sh4[NT * 32];        // [n][f4]  16 KB
  const float4* Wh4 = (const float4*)Wh;
  int ob = blockIdx.x;                   // o-tile (0..7)
  // stage Wh slice once
  for (int i = threadIdx.x; i < 128 * 32; i += 256){
    int f = i >> 5, ol = i & 31;
    sW[i] = Wh4[(long)f * 256 + ob * 32 + ol];
  }
  int o4l  = threadIdx.x & 31;
  int nsub = threadIdx.x >> 5;           // 0..7, 4 nodes each
  float4 mm = make_float4(-INFINITY, -INFINITY, -INFINITY, -INFINITY);
  int ntiles = (N + NT - 1) / NT;
  for (int nt = blockIdx.y; nt < ntiles; nt += gridDim.y){
    int n0 = nt * NT;
    __syncthreads();                     // protect sh4 (and cover sW on first iter)
    for (int i = threadIdx.x; i < NT * 32; i += 256){
      int n = i >> 5;
      float4 v = make_float4(0.f, 0.f, 0.f, 0.f);
      if (n0 + n < N) v = ((const float4*)h2)[(long)(n0 + n) * 32 + (i & 31)];
      sh4[i] = v;
    }
    __syncthreads();
    float4 acc[4];
#pragma unroll
    for (int j = 0; j < 4; j++) acc[j] = make_float4(0.f, 0.f, 0.f, 0.f);
#pragma unroll 4
    for (int f4 = 0; f4 < 32; f4++){
      float4 w0 = sW[(4 * f4 + 0) * 32 + o4l];
      float4 w1 = sW[(4 * f4 + 1) * 32 + o4l];
      float4 w2 = sW[(4 * f4 + 2) * 32 + o4l];
      float4 w3 = sW[(4 * f4 + 3) * 32 + o4l];
#pragma unroll
      for (int j = 0; j < 4; j++){
        float4 hv = sh4[(nsub * 4 + j) * 32 + f4];
        acc[j].x = fmaf(hv.x, w0.x, acc[j].x); acc[j].y = fmaf(hv.x, w0.y, acc[j].y);
        acc[j].z = fmaf(hv.x, w0.z, acc[j].z); acc[j].w = fmaf(hv.x, w0.w, acc[j].w);
        acc[j].x = fmaf(hv.y, w1.x, acc[j].x); acc[j].y = fmaf(hv.y, w1.y, acc[j].y);
        acc[j].z = fmaf(hv.y, w1.z, acc[j].z); acc[j].w = fmaf(hv.y, w1.w, acc[j].w);
        acc[j].x = fmaf(hv.z, w2.x, acc[j].x); acc[j].y = fmaf(hv.z, w2.y, acc[j].y);
        acc[j].z = fmaf(hv.z, w2.z, acc[j].z); acc[j].w = fmaf(hv.z, w2.w, acc[j].w);
        acc[j].x = fmaf(hv.w, w3.x, acc[j].x); acc[j].y = fmaf(hv.w, w3.y, acc[j].y);
        acc[j].z = fmaf(hv.w, w3.z, acc[j].z); acc[j].w = fmaf(hv.w, w3.w, acc[j].w);
      }
    }
#pragma unroll
    for (int j = 0; j < 4; j++){
      if (n0 + nsub * 4 + j < N){
        mm.x = fmaxf(mm.x, acc[j].x); mm.y = fmaxf(mm.y, acc[j].y);
        mm.z = fmaxf(mm.z, acc[j].z); mm.w = fmaxf(mm.w, acc[j].w);
      }
    }
  }
  // block reduce across nsub, one atomicMax per output
  __syncthreads();
  sh4[nsub * 32 + o4l] = mm;
  __syncthreads();
  if (nsub == 0){
#pragma unroll
    for (int s = 1; s < 8; s++){
      float4 o = sh4[s * 32 + o4l];
      mm.x = fmaxf(mm.x, o.x); mm.y = fmaxf(mm.y, o.y);
      mm.z = fmaxf(mm.z, o.z); mm.w = fmaxf(mm.w, o.w);
    }
    int o4 = ob * 32 + o4l;
    float4 b4 = ((const float4*)bh)[o4];
    atomicMax(&maxed[4 * o4 + 0], fmap(mm.x + b4.x));
    atomicMax(&maxed[4 * o4 + 1], fmap(mm.y + b4.y));
    atomicMax(&maxed[4 * o4 + 2], fmap(mm.z + b4.z));
    atomicMax(&maxed[4 * o4 + 3], fmap(mm.w + b4.w));
  }
}

__global__ __launch_bounds__(64) void k_final(const unsigned* __restrict__ maxed, const float* __restrict__ Wl,
                        const float* __restrict__ bl, float* __restrict__ out){
  int c = blockIdx.x;
  int l = threadIdx.x;
  float acc = 0.f;
  for (int o = l; o < 1024; o += 64)
    acc = fmaf(funmap(maxed[o]), Wl[o * NCLS + c], acc);
  for (int off = 32; off > 0; off >>= 1)
    acc += __shfl_down(acc, off);
  if (l == 0) out[c] = acc + bl[c];
}

// ================= drivers =================
static void run_scan(int* gh, int M, int* bsum, int* rp, int N, int E, hipStream_t s){
  int nb = cdiv(M, SCB);
  if (nb > 1) k_scanA<<<nb, 256, 0, s>>>(gh, M, bsum);
  k_scanC<<<nb, 256, 0, s>>>(gh, M, bsum, rp, N, E, nb);
}

template<int F, int FO, int R, bool RELU>
static void run_cheb(const int* row, const int* col, int E, int N,
                     const float* x, const float* W, const float* b, float* out,
                     unsigned* ebuf, int* cs, float* T, float4* xsA, float4* xsB,
                     int* rp, float* dinv, int* gh, int* bsum, hipStream_t s){
  int nbkt = cdiv(N, RPB);
  int chunk = cdiv(E, NBLK);
  k_phist<<<NBLK, 256, 0, s>>>(row, E, chunk, gh, nbkt);
  run_scan(gh, nbkt * NBLK, bsum, rp, N, E, s);
  k_pscatter<false><<<NBLK, 256, 0, s>>>(row, col, E, chunk, gh, ebuf, nbkt);
  // bfinal also computes dinv and prescales x into xsA
  k_bfinal<false, F><<<nbkt, 512, 0, s>>>(ebuf, gh, nbkt, N, E, nullptr, nullptr,
                                          rp, dinv, cs, nullptr, x, xsA);

  const float* sub = nullptr; float scale = 1.f;
  float4* xin = xsA; float4* xout = xsB;
  const float* srcRaw = x;
  for (int k = 1; k < KCH; k++){
    float* Tk = T + (size_t)(k - 1) * N * F;
    float4* xo = (k == KCH - 1) ? nullptr : xout;
    if constexpr (F == 3)
      k_gather3<<<cdiv((long)N * 8, 256), 256, 0, s>>>(rp, cs, xin, dinv, sub, Tk, xo, N, scale);
    else
      k_gatherT<F><<<cdiv((long)N * F, 256), 256, 0, s>>>(rp, cs, xin, dinv, sub, Tk, xo, N, scale);
    sub = srcRaw; srcRaw = Tk; scale = 2.f;
    float4* t = xin; xin = xout; xout = t;
  }
  constexpr int NTC = (256 / (FO / 4)) * R;
  k_cheb_tile<F, FO, R, RELU><<<cdiv(N, NTC), 256, 0, s>>>(x, T, N, W, b, out);
}

template<int F>
static void run_pool(const int* row, const int* col, const float* val, int E, int Nout,
                     const float* h, float* out, unsigned* ebuf, int* cs, float* wv,
                     int* rp, int* gh, int* bsum, hipStream_t s){
  int nbkt = cdiv(Nout, RPB);
  int chunk = cdiv(E, NBLK);
  k_phist<<<NBLK, 256, 0, s>>>(row, E, chunk, gh, nbkt);
  run_scan(gh, nbkt * NBLK, bsum, rp, Nout, E, s);
  k_pscatter<true><<<NBLK, 256, 0, s>>>(row, col, E, chunk, gh, ebuf, nbkt);
  k_bfinal<true, 0><<<nbkt, 512, 0, s>>>(ebuf, gh, nbkt, Nout, E, col, val,
                                         rp, nullptr, cs, wv, nullptr, nullptr);
  k_gatherP<F><<<cdiv((long)Nout * (F / 4), 256), 256, 0, s>>>(rp, cs, wv, h, out, Nout);
}

extern "C" void kernel_launch(void* const* d_in, const int* in_sizes, int n_in,
                              void* d_out, int out_size, void* d_ws, size_t ws_size,
                              hipStream_t stream){
  const float* pos = (const float*)d_in[0];
  const int*   ei0 = (const int*)d_in[1];
  const int*   ei1 = (const int*)d_in[2];
  const int*   ei2 = (const int*)d_in[3];
  const int*   p0r = (const int*)d_in[4];
  const int*   p0c = (const int*)d_in[5];
  const float* p0v = (const float*)d_in[6];
  const int*   p1r = (const int*)d_in[7];
  const int*   p1c = (const int*)d_in[8];
  const float* p1v = (const float*)d_in[9];
  const float* W0  = (const float*)d_in[10]; const float* b0 = (const float*)d_in[11];
  const float* W1  = (const float*)d_in[12]; const float* b1 = (const float*)d_in[13];
  const float* W2  = (const float*)d_in[14]; const float* b2 = (const float*)d_in[15];
  const float* Wh  = (const float*)d_in[16]; const float* bh = (const float*)d_in[17];
  const float* Wl  = (const float*)d_in[18]; const float* bl = (const float*)d_in[19];
  float* out = (float*)d_out;

  // workspace layout (float-sized units)
  float* SCR = (float*)d_ws;                 // 4.8M floats, per-stage overlays
  float* hA  = SCR + 4800000;                // 3.2M  (N0*32 / N2*128; L1 xs ping-pong)
  float* hB  = hA + 3200000;                 // 1.6M  (N1*64; L0 xs ping-pong)
  float* hC  = hB + 1600000;                 // 0.8M  (N1*32 / N2*64)
  int* rp     = (int*)(hC + 800000);         // 100001
  float* dinv = (float*)(rp + 100001);       // 100000
  int* gh     = (int*)(dinv + 100000);       // 47040 (196*240 max)
  int* bsum   = gh + 47040;                  // 16
  unsigned* maxed = (unsigned*)(bsum + 16);  // 1024

  // layer 0: cheb(pos) -> hA [N0,32], relu.
  run_cheb<3, 32, 2, true>(ei0, ei0 + E0G, E0G, N0G, pos, W0, b0, hA,
                        (unsigned*)SCR, (int*)(SCR + 1600000), SCR + 3200000,
                        (float4*)hB, (float4*)(hB + 400000),
                        rp, dinv, gh, bsum, stream);

  // pool 0: hA -> hC [N1,32].
  run_pool<32>(p0r, p0c, p0v, N0G, N1G, hA, hC,
               (unsigned*)SCR, (int*)(SCR + 100000), SCR + 200000,
               rp, gh, bsum, stream);

  // layer 1: cheb(hC) -> hB [N1,64], relu.
  run_cheb<32, 64, 2, true>(ei1, ei1 + E1G, E1G, N1G, hC, W1, b1, hB,
                         (unsigned*)SCR, (int*)(SCR + 400000), SCR + 800000,
                         (float4*)hA, (float4*)(hA + 800000),
                         rp, dinv, gh, bsum, stream);

  // pool 1: hB -> hC [N2,64].
  run_pool<64>(p1r, p1c, p1v, N1G, N2G, hB, hC,
               (unsigned*)SCR, (int*)(SCR + 25000), SCR + 50000,
               rp, gh, bsum, stream);

  // layer 2: cheb(hC) -> hA [N2,128], no relu.
  run_cheb<64, 128, 2, false>(ei2, ei2 + E2G, E2G, N2G, hC, W2, b2, hA,
                           (unsigned*)SCR, (int*)(SCR + 100000), SCR + 200000,
                           (float4*)(SCR + 2200000), (float4*)(SCR + 2600000),
                           rp, dinv, gh, bsum, stream);

  // hidden GEMM + global max over nodes
  hipMemsetAsync(maxed, 0, 1024 * sizeof(unsigned), stream);
  dim3 g(8, 64);
  k_hidden_max<<<g, 256, 0, stream>>>(hA, Wh, bh, maxed, N2G);

  // classifier
  k_final<<<NCLS, 64, 0, stream>>>(maxed, Wl, bl, out);
}

// Round 14
// 358.970 us; speedup vs baseline: 1.6328x; 1.2545x over previous
//
#include <hip/hip_runtime.h>
#include <cstdint>
#include <cmath>

#define N0G 100000
#define N1G 25000
#define N2G 6250
#define E0G 1600000
#define E1G 400000
#define E2G 100000
#define KCH 6
#define NCLS 40
#define RPB 512            // rows per bucket (9 bits local row)
#define NBLK 240           // binning blocks per stage
#define PAYB 17            // payload bits (col or edge idx < 131072)
#define SCT 16             // scan elems per thread
#define SCB (256 * SCT)    // scan elems per block
#define NST 5              // stages: L0,L1,L2,P0,P1

static inline int cdiv(long a, long b){ return (int)((a + b - 1) / b); }

struct BP {
  const int* row[NST]; const int* col[NST]; const float* pval[NST];
  unsigned* ebuf[NST]; int* cs[NST]; float* wv[NST]; int* rp[NST]; float* dinv[NST];
  int E[NST], N[NST], nbkt[NST], chunk[NST], ghoff[NST], pool[NST], nb[NST], bsumoff[NST];
  int blkS[NST + 1], blkB[NST + 1];
};

// ================= batched deterministic bucket CSR build =================
__global__ __launch_bounds__(256) void k_phist_b(BP p, int* __restrict__ gh){
  int s = blockIdx.x / NBLK, c = blockIdx.x % NBLK;
  const int* row = p.row[s];
  int E = p.E[s], nbkt = p.nbkt[s], chunk = p.chunk[s];
  int* g = gh + p.ghoff[s];
  __shared__ int h[256];
  for (int i = threadIdx.x; i < nbkt; i += 256) h[i] = 0;
  __syncthreads();
  int e0 = c * chunk, e1 = min(E, e0 + chunk);
  for (int e = e0 + threadIdx.x; e < e1; e += 256)
    atomicAdd(&h[row[e] >> 9], 1);
  __syncthreads();
  for (int i = threadIdx.x; i < nbkt; i += 256)
    g[i * NBLK + c] = h[i];
}

__global__ __launch_bounds__(256) void k_scanA_b(BP p, const int* __restrict__ gh, int* __restrict__ bsum){
  int s = 0; while (s < NST - 1 && (int)blockIdx.x >= p.blkS[s + 1]) s++;
  int lb = blockIdx.x - p.blkS[s];
  int M = p.nbkt[s] * NBLK;
  const int* g = gh + p.ghoff[s];
  __shared__ int sh[256];
  int base = lb * SCB + threadIdx.x * SCT;
  int su = 0;
#pragma unroll
  for (int j = 0; j < SCT; j++){ int i = base + j; if (i < M) su += g[i]; }
  sh[threadIdx.x] = su; __syncthreads();
  for (int o = 128; o > 0; o >>= 1){
    if (threadIdx.x < o) sh[threadIdx.x] += sh[threadIdx.x + o];
    __syncthreads();
  }
  if (threadIdx.x == 0) bsum[p.bsumoff[s] + lb] = sh[0];
}

__global__ __launch_bounds__(256) void k_scanC_b(BP p, int* __restrict__ gh, const int* __restrict__ bsum){
  int s = 0; while (s < NST - 1 && (int)blockIdx.x >= p.blkS[s + 1]) s++;
  int lb = blockIdx.x - p.blkS[s];
  int M = p.nbkt[s] * NBLK;
  int* g = gh + p.ghoff[s];
  __shared__ int sh[256];
  __shared__ int blockoff;
  if (threadIdx.x == 0){
    int off = 0;
    if (p.nb[s] > 1){
      const int* bs = bsum + p.bsumoff[s];
      for (int j = 0; j < lb; j++) off += bs[j];
    }
    blockoff = off;
  }
  int base = lb * SCB + threadIdx.x * SCT;
  int v[SCT]; int su = 0;
#pragma unroll
  for (int j = 0; j < SCT; j++){ int i = base + j; v[j] = (i < M) ? g[i] : 0; su += v[j]; }
  sh[threadIdx.x] = su;
  __syncthreads();
  for (int o = 1; o < 256; o <<= 1){
    int t = (threadIdx.x >= o) ? sh[threadIdx.x - o] : 0;
    __syncthreads();
    sh[threadIdx.x] += t;
    __syncthreads();
  }
  int excl = blockoff + sh[threadIdx.x] - su;
#pragma unroll
  for (int j = 0; j < SCT; j++){
    int i = base + j;
    if (i < M){ g[i] = excl; excl += v[j]; }
  }
  if (lb == 0 && threadIdx.x == 0) p.rp[s][p.N[s]] = p.E[s];
}

__global__ __launch_bounds__(256) void k_pscatter_b(BP p, const int* __restrict__ gh){
  int s = blockIdx.x / NBLK, c = blockIdx.x % NBLK;
  const int* row = p.row[s]; const int* col = p.col[s];
  int E = p.E[s], nbkt = p.nbkt[s], chunk = p.chunk[s], pool = p.pool[s];
  const int* g = gh + p.ghoff[s];
  unsigned* ebuf = p.ebuf[s];
  __shared__ int cur[256];
  for (int i = threadIdx.x; i < nbkt; i += 256) cur[i] = g[i * NBLK + c];
  __syncthreads();
  int e0 = c * chunk, e1 = min(E, e0 + chunk);
  for (int e = e0 + threadIdx.x; e < e1; e += 256){
    int r = row[e];
    int dst = atomicAdd(&cur[r >> 9], 1);
    unsigned pay = pool ? (unsigned)e : (unsigned)col[e];
    ebuf[dst] = ((unsigned)(r & 511) << PAYB) | pay;
  }
}

__global__ __launch_bounds__(512) void k_bfinal_b(BP p, const int* __restrict__ gh){
  int s = 0; while (s < NST - 1 && (int)blockIdx.x >= p.blkB[s + 1]) s++;
  int b = blockIdx.x - p.blkB[s];
  const int* g = gh + p.ghoff[s];
  const unsigned* ebuf = p.ebuf[s];
  int nbkt = p.nbkt[s], N = p.N[s], E = p.E[s], pool = p.pool[s];
  int* cs = p.cs[s]; float* wv = p.wv[s];
  int* rp = p.rp[s]; float* dinv = p.dinv[s];
  const int* pcol = p.col[s]; const float* pval = p.pval[s];
  __shared__ int h[512];
  __shared__ int cur[512];
  int e0 = g[b * NBLK];
  int e1 = (b + 1 < nbkt) ? g[(b + 1) * NBLK] : E;
  int r0 = b * RPB;
  int t = threadIdx.x;
  h[t] = 0;
  __syncthreads();
  for (int e = e0 + t; e < e1; e += 512)
    atomicAdd(&h[ebuf[e] >> PAYB], 1);
  __syncthreads();
  int cnt = h[t];
  __syncthreads();
  for (int o = 1; o < 512; o <<= 1){
    int tmp = (t >= o) ? h[t - o] : 0;
    __syncthreads();
    h[t] += tmp;
    __syncthreads();
  }
  int excl = h[t] - cnt;
  cur[t] = excl;
  int n = r0 + t;
  if (n < N){
    rp[n] = e0 + excl;
    if (!pool) dinv[n] = cnt > 0 ? rsqrtf((float)cnt) : 0.f;
  }
  __syncthreads();
  for (int e = e0 + t; e < e1; e += 512){
    unsigned u = ebuf[e];
    int pp = atomicAdd(&cur[u >> PAYB], 1);
    int dst = e0 + pp;
    if (pool){
      int ei = (int)(u & ((1u << PAYB) - 1));
      cs[dst] = pcol[ei]; wv[dst] = pval[ei];
    } else {
      cs[dst] = (int)(u & ((1u << PAYB) - 1));
    }
  }
}

// ================= prescale: xs[n] = dinv[n] * src[n] =================
__global__ __launch_bounds__(256) void k_prescale3(const float* __restrict__ x, const float* __restrict__ dinv,
                                                   float4* __restrict__ xs, int N){
  int n = blockIdx.x * 256 + threadIdx.x;
  if (n >= N) return;
  float d = dinv[n];
  xs[n] = make_float4(d * x[n * 3 + 0], d * x[n * 3 + 1], d * x[n * 3 + 2], 0.f);
}

template<int F>
__global__ __launch_bounds__(256) void k_prescaleF(const float* __restrict__ x, const float* __restrict__ dinv,
                                                   float4* __restrict__ xs, int N){
  constexpr int L = F / 4;
  int i = blockIdx.x * 256 + threadIdx.x;
  if (i >= N * L) return;
  float d = dinv[i / L];
  float4 v = ((const float4*)x)[i];
  xs[i] = make_float4(d * v.x, d * v.y, d * v.z, d * v.w);
}

// ================= CSR gathers (prescaled source, edge-split lanes) =================
__global__ __launch_bounds__(256) void k_gather3(const int* __restrict__ rp, const int* __restrict__ cs,
                          const float4* __restrict__ xs, const float* __restrict__ dinv,
                          const float* __restrict__ sub, float* __restrict__ dst,
                          float4* __restrict__ xs_out, int N, float scale){
  int tid = blockIdx.x * 256 + threadIdx.x;
  int n = tid >> 3, q = tid & 7;
  if (n >= N) return;
  int e0 = rp[n], e1 = rp[n + 1];
  float a0 = 0.f, a1 = 0.f, a2 = 0.f;
  for (int e = e0 + q; e < e1; e += 8){
    float4 v = xs[cs[e]];
    a0 += v.x; a1 += v.y; a2 += v.z;
  }
  a0 += __shfl_xor(a0, 1); a1 += __shfl_xor(a1, 1); a2 += __shfl_xor(a2, 1);
  a0 += __shfl_xor(a0, 2); a1 += __shfl_xor(a1, 2); a2 += __shfl_xor(a2, 2);
  a0 += __shfl_xor(a0, 4); a1 += __shfl_xor(a1, 4); a2 += __shfl_xor(a2, 4);
  if (q == 0){
    float dn = dinv[n];
    float m = -scale * dn;
    float r0 = m * a0, r1 = m * a1, r2 = m * a2;
    if (sub){ r0 -= sub[n * 3 + 0]; r1 -= sub[n * 3 + 1]; r2 -= sub[n * 3 + 2]; }
    dst[n * 3 + 0] = r0; dst[n * 3 + 1] = r1; dst[n * 3 + 2] = r2;
    if (xs_out) xs_out[n] = make_float4(dn * r0, dn * r1, dn * r2, 0.f);
  }
}

template<int F>
__global__ __launch_bounds__(256) void k_gatherT(const int* __restrict__ rp, const int* __restrict__ cs,
                          const float4* __restrict__ xs, const float* __restrict__ dinv,
                          const float* __restrict__ sub, float* __restrict__ dst,
                          float4* __restrict__ xs_out, int N, float scale){
  constexpr int L = F / 4;
  constexpr int G = 4 * L;
  int tid = blockIdx.x * 256 + threadIdx.x;
  int n = tid / G, q = tid % G;
  if (n >= N) return;
  int f4 = q % L, es = q / L;
  int e0 = rp[n], e1 = rp[n + 1];
  float4 acc = make_float4(0.f, 0.f, 0.f, 0.f);
  for (int e = e0 + es; e < e1; e += 4){
    float4 v = xs[(long)cs[e] * L + f4];
    acc.x += v.x; acc.y += v.y; acc.z += v.z; acc.w += v.w;
  }
  acc.x += __shfl_xor(acc.x, L);     acc.y += __shfl_xor(acc.y, L);
  acc.z += __shfl_xor(acc.z, L);     acc.w += __shfl_xor(acc.w, L);
  acc.x += __shfl_xor(acc.x, 2 * L); acc.y += __shfl_xor(acc.y, 2 * L);
  acc.z += __shfl_xor(acc.z, 2 * L); acc.w += __shfl_xor(acc.w, 2 * L);
  if (es == 0){
    float dn = dinv[n];
    float m = -scale * dn;
    float4 r = make_float4(m * acc.x, m * acc.y, m * acc.z, m * acc.w);
    if (sub){
      float4 sv = ((const float4*)sub)[(long)n * L + f4];
      r.x -= sv.x; r.y -= sv.y; r.z -= sv.z; r.w -= sv.w;
    }
    ((float4*)dst)[(long)n * L + f4] = r;
    if (xs_out) xs_out[(long)n * L + f4] = make_float4(dn * r.x, dn * r.y, dn * r.z, dn * r.w);
  }
}

template<int F>
__global__ __launch_bounds__(256) void k_gatherP(const int* __restrict__ rp, const int* __restrict__ cs,
                          const float* __restrict__ wv, const float* __restrict__ h,
                          float* __restrict__ dst, int N){
  constexpr int L = F / 4;
  int tid = blockIdx.x * 256 + threadIdx.x;
  int n = tid / L, q = tid % L;
  if (n >= N) return;
  const float4* h4 = (const float4*)h;
  int e0 = rp[n], e1 = rp[n + 1];
  float4 acc = make_float4(0.f, 0.f, 0.f, 0.f);
  for (int e = e0; e < e1; e++){
    int c = cs[e];
    float w = wv[e];
    float4 v = h4[(long)c * L + q];
    acc.x = fmaf(w, v.x, acc.x); acc.y = fmaf(w, v.y, acc.y);
    acc.z = fmaf(w, v.z, acc.z); acc.w = fmaf(w, v.w, acc.w);
  }
  ((float4*)dst)[(long)n * L + q] = acc;
}

// ================= dense cheb contraction, LDS-tiled =================
template<int F, int FO, int R, bool RELU>
__global__ __launch_bounds__(256) void k_cheb_tile(const float* __restrict__ x, const float* __restrict__ T, int N,
                           const float* __restrict__ W, const float* __restrict__ b,
                           float* __restrict__ out){
  constexpr int OQ4  = FO / 4;
  constexpr int NSUB = 256 / OQ4;
  constexpr int NT   = NSUB * R;
  constexpr int F6   = KCH * F;
  int n0 = blockIdx.x * NT;
  int o4   = threadIdx.x % OQ4;
  int nsub = threadIdx.x / OQ4;
  const float4* W4 = (const float4*)W;       // [F6][OQ4]
  float4 acc[R];
  float4 bb = ((const float4*)b)[o4];
#pragma unroll
  for (int r = 0; r < R; r++) acc[r] = bb;

  if constexpr (F == 3){
    constexpr int PITCH = F6 + 2;
    __shared__ float X[NT * PITCH];
    for (int i = threadIdx.x; i < NT * F6; i += 256){
      int k = i / (NT * 3);
      int idx = i - k * (NT * 3);
      const float* src = (k == 0) ? x : (T + (size_t)(k - 1) * N * 3);
      int node = idx / 3, j = idx - node * 3;
      float v = (n0 + node < N) ? src[(long)n0 * 3 + idx] : 0.f;
      X[node * PITCH + k * 3 + j] = v;
    }
    __syncthreads();
#pragma unroll
    for (int f = 0; f < F6; f++){
      float4 w = W4[(long)f * OQ4 + o4];
#pragma unroll
      for (int r = 0; r < R; r++){
        float v = X[(nsub * R + r) * PITCH + f];
        acc[r].x = fmaf(v, w.x, acc[r].x); acc[r].y = fmaf(v, w.y, acc[r].y);
        acc[r].z = fmaf(v, w.z, acc[r].z); acc[r].w = fmaf(v, w.w, acc[r].w);
      }
    }
  } else {
    constexpr int L  = F / 4;
    constexpr int P4 = F6 / 4 + 1;
    __shared__ float4 X[NT * P4];
    for (int i = threadIdx.x; i < NT * KCH * L; i += 256){
      int k = i / (NT * L);
      int idx = i - k * (NT * L);
      int node = idx / L, q = idx - node * L;
      const float4* src4 = (const float4*)((k == 0) ? x : (T + (size_t)(k - 1) * N * F));
      float4 v = make_float4(0.f, 0.f, 0.f, 0.f);
      if (n0 + node < N) v = src4[(long)n0 * L + idx];
      X[node * P4 + k * L + q] = v;
    }
    __syncthreads();
#pragma unroll 4
    for (int f4 = 0; f4 < F6 / 4; f4++){
      float4 w0 = W4[(long)(4 * f4 + 0) * OQ4 + o4];
      float4 w1 = W4[(long)(4 * f4 + 1) * OQ4 + o4];
      float4 w2 = W4[(long)(4 * f4 + 2) * OQ4 + o4];
      float4 w3 = W4[(long)(4 * f4 + 3) * OQ4 + o4];
#pragma unroll
      for (int r = 0; r < R; r++){
        float4 hv = X[(nsub * R + r) * P4 + f4];
        acc[r].x = fmaf(hv.x, w0.x, acc[r].x); acc[r].y = fmaf(hv.x, w0.y, acc[r].y);
        acc[r].z = fmaf(hv.x, w0.z, acc[r].z); acc[r].w = fmaf(hv.x, w0.w, acc[r].w);
        acc[r].x = fmaf(hv.y, w1.x, acc[r].x); acc[r].y = fmaf(hv.y, w1.y, acc[r].y);
        acc[r].z = fmaf(hv.y, w1.z, acc[r].z); acc[r].w = fmaf(hv.y, w1.w, acc[r].w);
        acc[r].x = fmaf(hv.z, w2.x, acc[r].x); acc[r].y = fmaf(hv.z, w2.y, acc[r].y);
        acc[r].z = fmaf(hv.z, w2.z, acc[r].z); acc[r].w = fmaf(hv.z, w2.w, acc[r].w);
        acc[r].x = fmaf(hv.w, w3.x, acc[r].x); acc[r].y = fmaf(hv.w, w3.y, acc[r].y);
        acc[r].z = fmaf(hv.w, w3.z, acc[r].z); acc[r].w = fmaf(hv.w, w3.w, acc[r].w);
      }
    }
  }

#pragma unroll
  for (int r = 0; r < R; r++){
    int n = n0 + nsub * R + r;
    if (n < N){
      float4 o = acc[r];
      if (RELU){
        o.x = fmaxf(o.x, 0.f); o.y = fmaxf(o.y, 0.f);
        o.z = fmaxf(o.z, 0.f); o.w = fmaxf(o.w, 0.f);
      }
      ((float4*)out)[(long)n * OQ4 + o4] = o;
    }
  }
}

// ================= final hidden GEMM + global max + classifier =================
__device__ __forceinline__ unsigned fmap(float x){
  unsigned u = __float_as_uint(x);
  return (u & 0x80000000u) ? ~u : (u | 0x80000000u);
}
__device__ __forceinline__ float funmap(unsigned u){
  return (u & 0x80000000u) ? __uint_as_float(u ^ 0x80000000u) : __uint_as_float(~u);
}

#define NT 32
__global__ __launch_bounds__(256) void k_hidden_max(const float* __restrict__ h2, const float* __restrict__ Wh,
                             const float* __restrict__ bh, unsigned* __restrict__ maxed, int N){
  __shared__ float4 sW[128 * 32];        // [f][o4l] 64 KB
  __shared__ float4 sh4[NT * 32];        // [n][f4]  16 KB
  const float4* Wh4 = (const float4*)Wh;
  int ob = blockIdx.x;
  for (int i = threadIdx.x; i < 128 * 32; i += 256){
    int f = i >> 5, ol = i & 31;
    sW[i] = Wh4[(long)f * 256 + ob * 32 + ol];
  }
  int o4l  = threadIdx.x & 31;
  int nsub = threadIdx.x >> 5;
  float4 mm = make_float4(-INFINITY, -INFINITY, -INFINITY, -INFINITY);
  int ntiles = (N + NT - 1) / NT;
  for (int nt = blockIdx.y; nt < ntiles; nt += gridDim.y){
    int n0 = nt * NT;
    __syncthreads();
    for (int i = threadIdx.x; i < NT * 32; i += 256){
      int n = i >> 5;
      float4 v = make_float4(0.f, 0.f, 0.f, 0.f);
      if (n0 + n < N) v = ((const float4*)h2)[(long)(n0 + n) * 32 + (i & 31)];
      sh4[i] = v;
    }
    __syncthreads();
    float4 acc[4];
#pragma unroll
    for (int j = 0; j < 4; j++) acc[j] = make_float4(0.f, 0.f, 0.f, 0.f);
#pragma unroll 4
    for (int f4 = 0; f4 < 32; f4++){
      float4 w0 = sW[(4 * f4 + 0) * 32 + o4l];
      float4 w1 = sW[(4 * f4 + 1) * 32 + o4l];
      float4 w2 = sW[(4 * f4 + 2) * 32 + o4l];
      float4 w3 = sW[(4 * f4 + 3) * 32 + o4l];
#pragma unroll
      for (int j = 0; j < 4; j++){
        float4 hv = sh4[(nsub * 4 + j) * 32 + f4];
        acc[j].x = fmaf(hv.x, w0.x, acc[j].x); acc[j].y = fmaf(hv.x, w0.y, acc[j].y);
        acc[j].z = fmaf(hv.x, w0.z, acc[j].z); acc[j].w = fmaf(hv.x, w0.w, acc[j].w);
        acc[j].x = fmaf(hv.y, w1.x, acc[j].x); acc[j].y = fmaf(hv.y, w1.y, acc[j].y);
        acc[j].z = fmaf(hv.y, w1.z, acc[j].z); acc[j].w = fmaf(hv.y, w1.w, acc[j].w);
        acc[j].x = fmaf(hv.z, w2.x, acc[j].x); acc[j].y = fmaf(hv.z, w2.y, acc[j].y);
        acc[j].z = fmaf(hv.z, w2.z, acc[j].z); acc[j].w = fmaf(hv.z, w2.w, acc[j].w);
        acc[j].x = fmaf(hv.w, w3.x, acc[j].x); acc[j].y = fmaf(hv.w, w3.y, acc[j].y);
        acc[j].z = fmaf(hv.w, w3.z, acc[j].z); acc[j].w = fmaf(hv.w, w3.w, acc[j].w);
      }
    }
#pragma unroll
    for (int j = 0; j < 4; j++){
      if (n0 + nsub * 4 + j < N){
        mm.x = fmaxf(mm.x, acc[j].x); mm.y = fmaxf(mm.y, acc[j].y);
        mm.z = fmaxf(mm.z, acc[j].z); mm.w = fmaxf(mm.w, acc[j].w);
      }
    }
  }
  __syncthreads();
  sh4[nsub * 32 + o4l] = mm;
  __syncthreads();
  if (nsub == 0){
#pragma unroll
    for (int s = 1; s < 8; s++){
      float4 o = sh4[s * 32 + o4l];
      mm.x = fmaxf(mm.x, o.x); mm.y = fmaxf(mm.y, o.y);
      mm.z = fmaxf(mm.z, o.z); mm.w = fmaxf(mm.w, o.w);
    }
    int o4 = ob * 32 + o4l;
    float4 b4 = ((const float4*)bh)[o4];
    atomicMax(&maxed[4 * o4 + 0], fmap(mm.x + b4.x));
    atomicMax(&maxed[4 * o4 + 1], fmap(mm.y + b4.y));
    atomicMax(&maxed[4 * o4 + 2], fmap(mm.z + b4.z));
    atomicMax(&maxed[4 * o4 + 3], fmap(mm.w + b4.w));
  }
}

__global__ __launch_bounds__(64) void k_final(const unsigned* __restrict__ maxed, const float* __restrict__ Wl,
                        const float* __restrict__ bl, float* __restrict__ out){
  int c = blockIdx.x;
  int l = threadIdx.x;
  float acc = 0.f;
  for (int o = l; o < 1024; o += 64)
    acc = fmaf(funmap(maxed[o]), Wl[o * NCLS + c], acc);
  for (int off = 32; off > 0; off >>= 1)
    acc += __shfl_down(acc, off);
  if (l == 0) out[c] = acc + bl[c];
}

// ================= flow driver (builds already done) =================
template<int F, int FO, int R, bool RELU>
static void run_flow(const int* rp, const int* cs, const float* dinv, int N,
                     const float* x, const float* W, const float* b, float* out,
                     float* T, float4* xsA, float4* xsB, hipStream_t s){
  if constexpr (F == 3)
    k_prescale3<<<cdiv(N, 256), 256, 0, s>>>(x, dinv, xsA, N);
  else
    k_prescaleF<F><<<cdiv((long)N * (F / 4), 256), 256, 0, s>>>(x, dinv, xsA, N);

  const float* sub = nullptr; float scale = 1.f;
  float4* xin = xsA; float4* xout = xsB;
  const float* srcRaw = x;
  for (int k = 1; k < KCH; k++){
    float* Tk = T + (size_t)(k - 1) * N * F;
    float4* xo = (k == KCH - 1) ? nullptr : xout;
    if constexpr (F == 3)
      k_gather3<<<cdiv((long)N * 8, 256), 256, 0, s>>>(rp, cs, xin, dinv, sub, Tk, xo, N, scale);
    else
      k_gatherT<F><<<cdiv((long)N * F, 256), 256, 0, s>>>(rp, cs, xin, dinv, sub, Tk, xo, N, scale);
    sub = srcRaw; srcRaw = Tk; scale = 2.f;
    float4* t = xin; xin = xout; xout = t;
  }
  constexpr int NTC = (256 / (FO / 4)) * R;
  k_cheb_tile<F, FO, R, RELU><<<cdiv(N, NTC), 256, 0, s>>>(x, T, N, W, b, out);
}

extern "C" void kernel_launch(void* const* d_in, const int* in_sizes, int n_in,
                              void* d_out, int out_size, void* d_ws, size_t ws_size,
                              hipStream_t stream){
  const float* pos = (const float*)d_in[0];
  const int*   ei0 = (const int*)d_in[1];
  const int*   ei1 = (const int*)d_in[2];
  const int*   ei2 = (const int*)d_in[3];
  const int*   p0r = (const int*)d_in[4];
  const int*   p0c = (const int*)d_in[5];
  const float* p0v = (const float*)d_in[6];
  const int*   p1r = (const int*)d_in[7];
  const int*   p1c = (const int*)d_in[8];
  const float* p1v = (const float*)d_in[9];
  const float* W0  = (const float*)d_in[10]; const float* b0 = (const float*)d_in[11];
  const float* W1  = (const float*)d_in[12]; const float* b1 = (const float*)d_in[13];
  const float* W2  = (const float*)d_in[14]; const float* b2 = (const float*)d_in[15];
  const float* Wh  = (const float*)d_in[16]; const float* bh = (const float*)d_in[17];
  const float* Wl  = (const float*)d_in[18]; const float* bl = (const float*)d_in[19];
  float* out = (float*)d_out;

  // ---- workspace layout (float units), ~12.33M floats = 49.3 MB ----
  float* TB = (float*)d_ws;                  // 4.0M : T region; ebufs (build) + L2 xs overlay
  float* hA = TB + 4000000;                  // 3.2M : L0 out [N0,32]; L1 xs ping-pong; L2 out [N2,128]
  float* hB = hA + 3200000;                  // 1.6M : L1 out [N1,64]; L0 xs ping-pong
  float* hC = hB + 1600000;                  // 0.8M : pool outs [N1,32]/[N2,64]
  int* cs0   = (int*)(hC + 800000);          // 1.6M
  int* cs1   = cs0 + 1600000;                // 400K
  int* cs2   = cs1 + 400000;                 // 100K
  int* csP0  = cs2 + 100000;                 // 100K
  int* csP1  = csP0 + 100000;                // 25K
  float* wvP0 = (float*)(csP1 + 25000);      // 100K
  float* wvP1 = wvP0 + 100000;               // 25K
  int* rp0  = (int*)(wvP1 + 25000);          // 100001
  int* rp1  = rp0 + 100001;                  // 25001
  int* rp2  = rp1 + 25001;                   // 6251
  int* rpP0 = rp2 + 6251;                    // 25001
  int* rpP1 = rpP0 + 25001;                  // 6251
  float* dv0 = (float*)(rpP1 + 6251);        // 100000
  float* dv1 = dv0 + 100000;                 // 25000
  float* dv2 = dv1 + 25000;                  // 6250
  int* gh   = (int*)(dv2 + 6250);            // 76800
  int* bsum = gh + 76800;                    // 80
  unsigned* maxed = (unsigned*)(bsum + 80);  // 1024

  // ebufs overlay the TB region (dead before any gather/T write)
  unsigned* eb0  = (unsigned*)TB;            // 1.6M
  unsigned* eb1  = eb0 + 1600000;            // 400K
  unsigned* eb2  = eb1 + 400000;             // 100K
  unsigned* ebP0 = eb2 + 100000;             // 100K
  unsigned* ebP1 = ebP0 + 100000;            // 25K

  // ---- batched CSR builds ----
  BP bp{};
  const int* rows[NST] = {ei0, ei1, ei2, p0r, p1r};
  const int* cols[NST] = {ei0 + E0G, ei1 + E1G, ei2 + E2G, p0c, p1c};
  const float* pvals[NST] = {nullptr, nullptr, nullptr, p0v, p1v};
  unsigned* ebufs[NST] = {eb0, eb1, eb2, ebP0, ebP1};
  int* css[NST] = {cs0, cs1, cs2, csP0, csP1};
  float* wvs[NST] = {nullptr, nullptr, nullptr, wvP0, wvP1};
  int* rps[NST] = {rp0, rp1, rp2, rpP0, rpP1};
  float* dvs[NST] = {dv0, dv1, dv2, nullptr, nullptr};
  int Es[NST] = {E0G, E1G, E2G, N0G, N1G};
  int Ns[NST] = {N0G, N1G, N2G, N1G, N2G};
  int pools[NST] = {0, 0, 0, 1, 1};
  int ghacc = 0, scanacc = 0, bacc = 0;
  bp.blkS[0] = 0; bp.blkB[0] = 0;
  for (int s = 0; s < NST; s++){
    bp.row[s] = rows[s]; bp.col[s] = cols[s]; bp.pval[s] = pvals[s];
    bp.ebuf[s] = ebufs[s]; bp.cs[s] = css[s]; bp.wv[s] = wvs[s];
    bp.rp[s] = rps[s]; bp.dinv[s] = dvs[s];
    bp.E[s] = Es[s]; bp.N[s] = Ns[s]; bp.pool[s] = pools[s];
    bp.nbkt[s] = cdiv(Ns[s], RPB);
    bp.chunk[s] = cdiv(Es[s], NBLK);
    bp.ghoff[s] = ghacc; ghacc += bp.nbkt[s] * NBLK;
    bp.nb[s] = cdiv(bp.nbkt[s] * NBLK, SCB);
    bp.bsumoff[s] = s * 16;
    scanacc += bp.nb[s]; bp.blkS[s + 1] = scanacc;
    bacc += bp.nbkt[s]; bp.blkB[s + 1] = bacc;
  }

  k_phist_b<<<NST * NBLK, 256, 0, stream>>>(bp, gh);
  k_scanA_b<<<scanacc, 256, 0, stream>>>(bp, gh, bsum);
  k_scanC_b<<<scanacc, 256, 0, stream>>>(bp, gh, bsum);
  k_pscatter_b<<<NST * NBLK, 256, 0, stream>>>(bp, gh);
  k_bfinal_b<<<bacc, 512, 0, stream>>>(bp, gh);

  hipMemsetAsync(maxed, 0, 1024 * sizeof(unsigned), stream);

  // ---- dataflow ----
  // layer 0: cheb(pos) -> hA [N0,32]; T=1.5M in TB; xs ping-pong in hB
  run_flow<3, 32, 2, true>(rp0, cs0, dv0, N0G, pos, W0, b0, hA,
                           TB, (float4*)hB, (float4*)(hB + 400000), stream);

  // pool 0: hA -> hC [N1,32]
  k_gatherP<32><<<cdiv((long)N1G * 8, 256), 256, 0, stream>>>(rpP0, csP0, wvP0, hA, hC, N1G);

  // layer 1: cheb(hC) -> hB [N1,64]; T=4.0M in TB; xs ping-pong in hA (free now)
  run_flow<32, 64, 2, true>(rp1, cs1, dv1, N1G, hC, W1, b1, hB,
                            TB, (float4*)hA, (float4*)(hA + 800000), stream);

  // pool 1: hB -> hC [N2,64]
  k_gatherP<64><<<cdiv((long)N2G * 16, 256), 256, 0, stream>>>(rpP1, csP1, wvP1, hB, hC, N2G);

  // layer 2: cheb(hC) -> hA [N2,128]; T=2.0M in TB; xs ping-pong at TB+2.4M
  run_flow<64, 128, 2, false>(rp2, cs2, dv2, N2G, hC, W2, b2, hA,
                              TB, (float4*)(TB + 2400000), (float4*)(TB + 2800000), stream);

  // hidden GEMM + global max over nodes
  dim3 g(8, 64);
  k_hidden_max<<<g, 256, 0, stream>>>(hA, Wh, bh, maxed, N2G);

  // classifier
  k_final<<<NCLS, 64, 0, stream>>>(maxed, Wl, bl, out);
}